// Round 9
// baseline (5599.716 us; speedup 1.0000x reference)
//
#include <hip/hip_runtime.h>
#include <hip/hip_bf16.h>
#include <math.h>

// Problem constants
#define Bn  4
#define Cc  64
#define MHc 18
#define Hh  128
#define Wd  128
#define HW  (Hh*Wd)
#define Np  9

// Dtype model (H5, from R1-R8 evidence matrix): ALL inputs f32 (any partial
// bf16 read NaN'd in R6/R7/R8 -> every buffer is f32); outputs f32 (expected
// is bf16-rounded but stored/compared in f32 -> threshold floor_eps_k=8).
// R4/R5's identical 7.335938 = harness reading our bf16 stores as f32 pairs.
// Per-buffer runtime sniff retained as a safety net.
__device__ __forceinline__ float bf2f(__hip_bfloat16 x) { return __bfloat162float(x); }

// per-block dtype sniff: sets *flag if halfwords are implausible as bf16
// (=> buffer is f32). All threads participate; caller syncs.
__device__ __forceinline__ void sniff(const void* p, int nelem, int* flag) {
  int K = nelem < 2048 ? nelem : 2048;
  const unsigned short* hp = (const unsigned short*)p;
  int bad = 0;
  for (int i = threadIdx.x; i < K; i += blockDim.x) {
    int ex = (hp[i] >> 7) & 0xFF;
    if (ex == 0xFF || (ex != 0 && (ex < 97 || ex > 135))) bad = 1;
  }
  if (bad) atomicOr(flag, 1);
}

__device__ __forceinline__ float ldv(const void* p, int i, int isf32) {
  return isf32 ? ((const float*)p)[i]
               : bf2f(((const __hip_bfloat16*)p)[i]);
}

// ---------------------------------------------------------------------------
// K1: update & reset gate convs (3x3, pad1, Cin=82) -> u (f32), r*po (f32)
// Scratch lives in the out_x region of d_out (aliasing proven safe: R4==R5).
// ---------------------------------------------------------------------------
__global__ void k_convAB(const void* __restrict__ x,
                         const void* __restrict__ po,
                         const void* __restrict__ wA,
                         const void* __restrict__ bA,
                         const void* __restrict__ wB,
                         const void* __restrict__ bB,
                         float* __restrict__ u_scr,
                         float* __restrict__ ro_scr) {
  __shared__ int fb[6];
  if (threadIdx.x < 6) fb[threadIdx.x] = 0;
  __syncthreads();
  sniff(x,  Bn*Cc*HW,  &fb[0]);
  sniff(po, Bn*MHc*HW, &fb[1]);
  sniff(wA, MHc*(Cc+MHc)*9, &fb[2]);
  sniff(bA, MHc, &fb[3]);
  sniff(wB, MHc*(Cc+MHc)*9, &fb[4]);
  sniff(bB, MHc, &fb[5]);
  __syncthreads();
  int fx = fb[0], fp = fb[1], fwa = fb[2], fba = fb[3], fwb = fb[4], fbb = fb[5];

  int idx = blockIdx.x * 256 + threadIdx.x;
  const int total = Bn * MHc * HW;
  if (idx >= total) return;
  int w  = idx & 127;
  int h  = (idx >> 7) & 127;
  int oc = (idx >> 14) % MHc;
  int b  = idx / (MHc * HW);
  float accA = ldv(bA, oc, fba);
  float accB = ldv(bB, oc, fbb);
  for (int ic = 0; ic < Cc + MHc; ++ic) {
    #pragma unroll
    for (int kh = 0; kh < 3; ++kh) {
      int hh = h + kh - 1;
      if ((unsigned)hh >= (unsigned)Hh) continue;
      #pragma unroll
      for (int kw = 0; kw < 3; ++kw) {
        int ww = w + kw - 1;
        if ((unsigned)ww >= (unsigned)Wd) continue;
        float v = (ic < Cc)
            ? ldv(x,  (b*Cc + ic)*HW + hh*Wd + ww, fx)
            : ldv(po, (b*MHc + (ic-Cc))*HW + hh*Wd + ww, fp);
        accA += v * ldv(wA, (oc*(Cc+MHc) + ic)*9 + kh*3 + kw, fwa);
        accB += v * ldv(wB, (oc*(Cc+MHc) + ic)*9 + kh*3 + kw, fwb);
      }
    }
  }
  float u = 1.f / (1.f + expf(-accA));
  float r = 1.f / (1.f + expf(-accB));
  u_scr[idx]  = u;
  ro_scr[idx] = r * ldv(po, idx, fp);
}

// ---------------------------------------------------------------------------
// K2: candidate conv (x 64ch + ro 18ch); fuse offset & mean; outputs f32.
// ---------------------------------------------------------------------------
__global__ void k_convC(const void* __restrict__ x,
                        const void* __restrict__ po,
                        const void* __restrict__ mean,
                        const void* __restrict__ wC,
                        const void* __restrict__ bC,
                        const float* __restrict__ u_scr,
                        const float* __restrict__ ro_scr,
                        float* __restrict__ out_off,
                        float* __restrict__ out_mean) {
  __shared__ int fb[5];
  if (threadIdx.x < 5) fb[threadIdx.x] = 0;
  __syncthreads();
  sniff(x,    Bn*Cc*HW,  &fb[0]);
  sniff(po,   Bn*MHc*HW, &fb[1]);
  sniff(mean, Bn*MHc*HW, &fb[2]);
  sniff(wC,   MHc*(Cc+MHc)*9, &fb[3]);
  sniff(bC,   MHc, &fb[4]);
  __syncthreads();
  int fx = fb[0], fp = fb[1], fm = fb[2], fwc = fb[3], fbc = fb[4];

  int idx = blockIdx.x * 256 + threadIdx.x;
  const int total = Bn * MHc * HW;
  if (idx >= total) return;
  int w  = idx & 127;
  int h  = (idx >> 7) & 127;
  int oc = (idx >> 14) % MHc;
  int b  = idx / (MHc * HW);
  float acc = ldv(bC, oc, fbc);
  const float* rb = ro_scr + b * MHc * HW;
  for (int ic = 0; ic < Cc + MHc; ++ic) {
    #pragma unroll
    for (int kh = 0; kh < 3; ++kh) {
      int hh = h + kh - 1;
      if ((unsigned)hh >= (unsigned)Hh) continue;
      #pragma unroll
      for (int kw = 0; kw < 3; ++kw) {
        int ww = w + kw - 1;
        if ((unsigned)ww >= (unsigned)Wd) continue;
        float v = (ic < Cc) ? ldv(x, (b*Cc + ic)*HW + hh*Wd + ww, fx)
                            : rb[(ic-Cc)*HW + hh*Wd + ww];
        acc += v * ldv(wC, (oc*(Cc+MHc) + ic)*9 + kh*3 + kw, fwc);
      }
    }
  }
  float cand = tanhf(acc);
  float u = u_scr[idx];
  float p = ldv(po, idx, fp);
  float mn = 0.5f * (ldv(mean, idx, fm) + p);
  float off = p * (1.f - u) + cand * u + mn;
  out_off[idx]  = off;
  out_mean[idx] = mn;
}

// ---------------------------------------------------------------------------
// K3: fused warp, fully scalar. Block = 4 waves; wave owns one pixel.
//  stage 1: modulation gate m[9] (lane = channel)
//  stage 2: deformable bilinear gather -> xw[9][64] in LDS (lane = channel)
//  stage 3: 576-term dot per output channel (lane = co), write out_x (f32).
// ---------------------------------------------------------------------------
__global__ __launch_bounds__(256)
void k_warp_s(const void* __restrict__ x,
              const float* __restrict__ off_f,
              const void* __restrict__ wg,
              const void* __restrict__ bg,
              const void* __restrict__ wc,
              float* __restrict__ out) {
  __shared__ int fb[4];
  __shared__ float mred[4][Np][64];
  __shared__ float mval[4][Np];
  __shared__ float xwv[4][Np][64];
  if (threadIdx.x < 4) fb[threadIdx.x] = 0;
  __syncthreads();
  sniff(x,  Bn*Cc*HW, &fb[0]);
  sniff(wg, Np*Cc*9,  &fb[1]);
  sniff(bg, Np,       &fb[2]);
  sniff(wc, Cc*Cc*9,  &fb[3]);
  __syncthreads();
  int fx = fb[0], fwg = fb[1], fbg = fb[2], fwc = fb[3];

  int lane = threadIdx.x & 63;
  int wave = threadIdx.x >> 6;
  int p = blockIdx.x * 4 + wave;          // pixel id, < 65536
  int b = p >> 14;
  int rem = p & 16383;
  int h = rem >> 7;
  int w = rem & 127;

  const int xbase = (b*Cc + lane) * HW;   // this lane's channel plane

  // ---- stage 1: modulation-gate conv partials (channel = lane) ----
  float part[Np];
  #pragma unroll
  for (int n = 0; n < Np; ++n) part[n] = 0.f;
  #pragma unroll
  for (int kh = 0; kh < 3; ++kh) {
    int hh = h + kh - 1;
    if ((unsigned)hh >= (unsigned)Hh) continue;
    #pragma unroll
    for (int kw = 0; kw < 3; ++kw) {
      int ww = w + kw - 1;
      if ((unsigned)ww >= (unsigned)Wd) continue;
      float v = ldv(x, xbase + hh*Wd + ww, fx);
      #pragma unroll
      for (int n = 0; n < Np; ++n)
        part[n] += v * ldv(wg, (n*Cc + lane)*9 + kh*3 + kw, fwg);
    }
  }
  #pragma unroll
  for (int n = 0; n < Np; ++n) mred[wave][n][lane] = part[n];
  __syncthreads();
  if (lane < Np) {
    float s = ldv(bg, lane, fbg);
    for (int c = 0; c < Cc; ++c) s += mred[wave][lane][c];
    mval[wave][lane] = 1.f / (1.f + expf(-s));
  }
  __syncthreads();

  // ---- stage 2: deformable bilinear gather (channel = lane) ----
  const float* offb = off_f + b * MHc * HW;
  int sp = h * Wd + w;
  #pragma unroll
  for (int n = 0; n < Np; ++n) {
    float ox = offb[n * HW + sp];
    float oy = offb[(9 + n) * HW + sp];
    float px = (float)(h + 1) + (float)(n / 3 - 1) + ox;   // padded coords
    float py = (float)(w + 1) + (float)(n % 3 - 1) + oy;
    float fxq = floorf(px), fyq = floorf(py);
    float xlt = fminf(fmaxf(fxq,       0.f), 129.f);
    float ylt = fminf(fmaxf(fyq,       0.f), 129.f);
    float xrb = fminf(fmaxf(fxq + 1.f, 0.f), 129.f);
    float yrb = fminf(fmaxf(fyq + 1.f, 0.f), 129.f);
    float pxc = fminf(fmaxf(px, 0.f), 129.f);
    float pyc = fminf(fmaxf(py, 0.f), 129.f);
    float glt = (1.f + xlt - pxc) * (1.f + ylt - pyc);
    float grb = (1.f - xrb + pxc) * (1.f - yrb + pyc);
    float glb = (1.f + xlt - pxc) * (1.f - yrb + pyc);
    float grt = (1.f - xrb + pxc) * (1.f + ylt - pyc);
    int ixl = (int)xlt, iyl = (int)ylt, ixr = (int)xrb, iyr = (int)yrb;
    // implicit zero pad: padded coord q maps to x[q-1], valid iff 1<=q<=128
    float vlt = 0.f, vrb = 0.f, vlb = 0.f, vrt = 0.f;
    if (ixl >= 1 && ixl <= Hh && iyl >= 1 && iyl <= Wd)
      vlt = ldv(x, xbase + (ixl-1)*Wd + (iyl-1), fx);
    if (ixr >= 1 && ixr <= Hh && iyr >= 1 && iyr <= Wd)
      vrb = ldv(x, xbase + (ixr-1)*Wd + (iyr-1), fx);
    if (ixl >= 1 && ixl <= Hh && iyr >= 1 && iyr <= Wd)
      vlb = ldv(x, xbase + (ixl-1)*Wd + (iyr-1), fx);
    if (ixr >= 1 && ixr <= Hh && iyl >= 1 && iyl <= Wd)
      vrt = ldv(x, xbase + (ixr-1)*Wd + (iyl-1), fx);
    float xw = (glt*vlt + grb*vrb + glb*vlb + grt*vrt) * mval[wave][n];
    xwv[wave][n][lane] = xw;
  }
  __syncthreads();

  // ---- stage 3: per-co dot product over k = (n, ci) (co = lane) ----
  float acc = 0.f;
  for (int c = 0; c < Cc; ++c) {
    #pragma unroll
    for (int n = 0; n < Np; ++n)
      acc += xwv[wave][n][c] * ldv(wc, (lane*Cc + c)*9 + n, fwc);
  }
  out[(b*Cc + lane)*HW + h*Wd + w] = acc;
}

// ---------------------------------------------------------------------------
extern "C" void kernel_launch(void* const* d_in, const int* in_sizes, int n_in,
                              void* d_out, int out_size, void* d_ws, size_t ws_size,
                              hipStream_t stream) {
  (void)in_sizes; (void)n_in; (void)out_size; (void)d_ws; (void)ws_size;
  // H5: all inputs f32 (runtime sniff as safety net), outputs f32.
  float* out_x   = (float*)d_out;            // [4,64,128,128]
  float* out_off = out_x + 4194304;          // [4,18,128,128]
  float* out_mn  = out_off + 1179648;        // [4,18,128,128]

  // Scratch inside the out_x region (16,777,216 B as f32): u f32 then ro f32
  // (2 x 4,718,592 B). Consumed only by k_convC, then the whole region is
  // overwritten by k_warp_s. Zero d_ws usage.
  float* u_scr  = out_x;
  float* ro_scr = out_x + 1179648;

  hipLaunchKernelGGL(k_convAB, dim3(4608),  dim3(256), 0, stream,
                     d_in[0], d_in[1], d_in[3], d_in[4], d_in[5], d_in[6],
                     u_scr, ro_scr);
  hipLaunchKernelGGL(k_convC,  dim3(4608),  dim3(256), 0, stream,
                     d_in[0], d_in[1], d_in[2], d_in[7], d_in[8],
                     u_scr, ro_scr, out_off, out_mn);
  hipLaunchKernelGGL(k_warp_s, dim3(16384), dim3(256), 0, stream,
                     d_in[0], out_off, d_in[9], d_in[10], d_in[11], out_x);
}

// Round 10
// 1035.043 us; speedup vs baseline: 5.4101x; 5.4101x over previous
//
#include <hip/hip_runtime.h>
#include <hip/hip_bf16.h>
#include <math.h>

// Problem constants
#define Bn  4
#define Cc  64
#define MHc 18
#define Hh  128
#define Wd  128
#define HW  (Hh*Wd)
#define Np  9
#define HP  130
#define WP  130
#define XPADE (HP*WP*Cc)            // 1,081,600 floats per batch

typedef __attribute__((ext_vector_type(8))) short short8;
typedef __attribute__((ext_vector_type(4))) float float4v;

__device__ __forceinline__ float bf2f(__hip_bfloat16 x) { return __bfloat162float(x); }
__device__ __forceinline__ __hip_bfloat16 f2bf(float x) { return __float2bfloat16(x); }

// ---------------------------------------------------------------------------
// K0: zero the padded channels-last buffer (borders must be 0)
// ---------------------------------------------------------------------------
__global__ void k_zero(float* __restrict__ xp) {
  int idx = blockIdx.x * 256 + threadIdx.x;
  if (idx < Bn * XPADE) xp[idx] = 0.f;
}

// ---------------------------------------------------------------------------
// K1: LDS-tiled transpose x[B,C,H,W] -> xpad[B,HP,WP,C] (interior only).
// Block = (b, h, 16-wide w tile). Phase A coalesced NCHW reads -> LDS;
// Phase B coalesced channels-last writes (256 B per pixel).
// ---------------------------------------------------------------------------
__global__ __launch_bounds__(256)
void k_prep(const float* __restrict__ x, float* __restrict__ xp) {
  __shared__ float tile[16][65];
  int blk = blockIdx.x;
  int wtile = blk & 7;
  int h = (blk >> 3) & 127;
  int b = blk >> 10;
  int w0 = wtile * 16;
  int t = threadIdx.x;

  int wa = t & 15, cq = t >> 4;          // phase A: 16 w x 16 c-groups
  #pragma unroll
  for (int j = 0; j < 4; ++j) {
    int c = cq * 4 + j;
    tile[wa][c] = x[(b*Cc + c)*HW + h*Wd + w0 + wa];
  }
  __syncthreads();
  int cb = t & 63, wq = t >> 6;          // phase B: 64 c x 4 w-groups
  #pragma unroll
  for (int j = 0; j < 4; ++j) {
    int w = wq * 4 + j;
    xp[b*XPADE + ((h+1)*WP + (w0 + w + 1))*Cc + cb] = tile[w][cb];
  }
}

// ---------------------------------------------------------------------------
// K2: reorder+cast warp_conv_w [co][ci][n] -> wt_bf[co][k], k = n*64 + ci
// ---------------------------------------------------------------------------
__global__ void k_wt(const float* __restrict__ w,
                     __hip_bfloat16* __restrict__ wt) {
  int idx = blockIdx.x * 256 + threadIdx.x;
  if (idx >= Cc * Cc * Np) return;
  int k  = idx % 576;
  int co = idx / 576;
  int n  = k >> 6;
  int ci = k & 63;
  wt[idx] = f2bf(w[(co*Cc + ci)*9 + n]);
}

// ---------------------------------------------------------------------------
// K3: update & reset gate convs (3x3, pad1, Cin=82) -> u (f32), r*po (f32)
// Scratch in the out_x region of d_out (proven safe; overwritten last).
// ---------------------------------------------------------------------------
__global__ __launch_bounds__(256)
void k_convAB(const float* __restrict__ x,
              const float* __restrict__ po,
              const float* __restrict__ wA,
              const float* __restrict__ bA,
              const float* __restrict__ wB,
              const float* __restrict__ bB,
              float* __restrict__ u_scr,
              float* __restrict__ ro_scr) {
  int idx = blockIdx.x * 256 + threadIdx.x;
  const int total = Bn * MHc * HW;
  if (idx >= total) return;
  int w  = idx & 127;
  int h  = (idx >> 7) & 127;
  int oc = (idx >> 14) % MHc;
  int b  = idx / (MHc * HW);
  float accA = bA[oc];
  float accB = bB[oc];
  const float* xb = x  + b * Cc  * HW;
  const float* pb = po + b * MHc * HW;
  for (int ic = 0; ic < Cc + MHc; ++ic) {
    const float* src = (ic < Cc) ? (xb + ic*HW) : (pb + (ic-Cc)*HW);
    const float* wa = wA + (oc*(Cc+MHc) + ic) * 9;
    const float* wb = wB + (oc*(Cc+MHc) + ic) * 9;
    #pragma unroll
    for (int kh = 0; kh < 3; ++kh) {
      int hh = h + kh - 1;
      if ((unsigned)hh >= (unsigned)Hh) continue;
      #pragma unroll
      for (int kw = 0; kw < 3; ++kw) {
        int ww = w + kw - 1;
        if ((unsigned)ww >= (unsigned)Wd) continue;
        float v = src[hh*Wd + ww];
        accA += v * wa[kh*3 + kw];
        accB += v * wb[kh*3 + kw];
      }
    }
  }
  float u = 1.f / (1.f + expf(-accA));
  float r = 1.f / (1.f + expf(-accB));
  u_scr[idx]  = u;
  ro_scr[idx] = r * pb[oc*HW + h*Wd + w];
}

// ---------------------------------------------------------------------------
// K4: modulation gate conv m = sigmoid(conv3x3(x)+bg) -> m_ws [B,9,H,W] f32
// ---------------------------------------------------------------------------
__global__ __launch_bounds__(256)
void k_convM(const float* __restrict__ x,
             const float* __restrict__ wg,
             const float* __restrict__ bg,
             float* __restrict__ m_ws) {
  int idx = blockIdx.x * 256 + threadIdx.x;
  const int total = Bn * Np * HW;
  if (idx >= total) return;
  int w = idx & 127;
  int h = (idx >> 7) & 127;
  int n = (idx >> 14) % Np;
  int b = idx / (Np * HW);
  float acc = bg[n];
  const float* xb = x + b * Cc * HW;
  for (int ic = 0; ic < Cc; ++ic) {
    const float* src = xb + ic * HW;
    const float* wv  = wg + (n*Cc + ic) * 9;
    #pragma unroll
    for (int kh = 0; kh < 3; ++kh) {
      int hh = h + kh - 1;
      if ((unsigned)hh >= (unsigned)Hh) continue;
      #pragma unroll
      for (int kw = 0; kw < 3; ++kw) {
        int ww = w + kw - 1;
        if ((unsigned)ww >= (unsigned)Wd) continue;
        acc += src[hh*Wd + ww] * wv[kh*3 + kw];
      }
    }
  }
  m_ws[idx] = 1.f / (1.f + expf(-acc));
}

// ---------------------------------------------------------------------------
// K5: candidate conv; fuse offset & mean; outputs f32.
// ---------------------------------------------------------------------------
__global__ __launch_bounds__(256)
void k_convC(const float* __restrict__ x,
             const float* __restrict__ po,
             const float* __restrict__ mean,
             const float* __restrict__ wC,
             const float* __restrict__ bC,
             const float* __restrict__ u_scr,
             const float* __restrict__ ro_scr,
             float* __restrict__ out_off,
             float* __restrict__ out_mean) {
  int idx = blockIdx.x * 256 + threadIdx.x;
  const int total = Bn * MHc * HW;
  if (idx >= total) return;
  int w  = idx & 127;
  int h  = (idx >> 7) & 127;
  int oc = (idx >> 14) % MHc;
  int b  = idx / (MHc * HW);
  float acc = bC[oc];
  const float* xb = x + b * Cc * HW;
  const float* rb = ro_scr + b * MHc * HW;
  for (int ic = 0; ic < Cc + MHc; ++ic) {
    const float* src = (ic < Cc) ? (xb + ic*HW) : (rb + (ic-Cc)*HW);
    const float* wv = wC + (oc*(Cc+MHc) + ic) * 9;
    #pragma unroll
    for (int kh = 0; kh < 3; ++kh) {
      int hh = h + kh - 1;
      if ((unsigned)hh >= (unsigned)Hh) continue;
      #pragma unroll
      for (int kw = 0; kw < 3; ++kw) {
        int ww = w + kw - 1;
        if ((unsigned)ww >= (unsigned)Wd) continue;
        acc += src[hh*Wd + ww] * wv[kh*3 + kw];
      }
    }
  }
  float cand = tanhf(acc);
  float u = u_scr[idx];
  float p = po[idx];
  float mn = 0.5f * (mean[idx] + p);
  float off = p * (1.f - u) + cand * u + mn;
  out_off[idx]  = off;
  out_mean[idx] = mn;
}

// ---------------------------------------------------------------------------
// K6: deformable gather (coalesced channels-last) + MFMA 64x576 GEMM.
// Block = (b, h, 16-pixel w tile), 4 waves. Gather: wave owns 4 pixels,
// lane = channel -> each corner read is one contiguous 256B segment.
// GEMM: wave w computes co-tile [16w,16w+16) x 16 pixels, K=576 in 18 MFMAs.
// ---------------------------------------------------------------------------
__global__ __launch_bounds__(256)
void k_warp_m(const float* __restrict__ xpad,
              const float* __restrict__ off_f,
              const float* __restrict__ m_ws,
              const __hip_bfloat16* __restrict__ wt,
              float* __restrict__ out) {
  __shared__ __align__(16) __hip_bfloat16 sh[16][584];  // 576 + 8 pad
  int blk = blockIdx.x;
  int wtile = blk & 7;
  int h = (blk >> 3) & 127;
  int b = blk >> 10;
  int w0 = wtile * 16;
  int lane = threadIdx.x & 63;
  int wave = threadIdx.x >> 6;

  const float* xpb  = xpad + b * XPADE;
  const float* offb = off_f + b * MHc * HW;
  const float* mb   = m_ws  + b * Np  * HW;

  for (int t = 0; t < 4; ++t) {
    int pl = wave * 4 + t;
    int wp = w0 + pl;
    int sp = h * Wd + wp;
    #pragma unroll
    for (int n = 0; n < Np; ++n) {
      float ox = offb[n * HW + sp];
      float oy = offb[(9 + n) * HW + sp];
      float mn = mb[n * HW + sp];
      float px = (float)(h + 1) + (float)(n / 3 - 1) + ox;
      float py = (float)(wp + 1) + (float)(n % 3 - 1) + oy;
      float fx = floorf(px), fy = floorf(py);
      float xlt = fminf(fmaxf(fx,       0.f), 129.f);
      float ylt = fminf(fmaxf(fy,       0.f), 129.f);
      float xrb = fminf(fmaxf(fx + 1.f, 0.f), 129.f);
      float yrb = fminf(fmaxf(fy + 1.f, 0.f), 129.f);
      float pxc = fminf(fmaxf(px, 0.f), 129.f);
      float pyc = fminf(fmaxf(py, 0.f), 129.f);
      float glt = (1.f + xlt - pxc) * (1.f + ylt - pyc);
      float grb = (1.f - xrb + pxc) * (1.f - yrb + pyc);
      float glb = (1.f + xlt - pxc) * (1.f - yrb + pyc);
      float grt = (1.f - xrb + pxc) * (1.f + ylt - pyc);
      int ixl = (int)xlt, iyl = (int)ylt, ixr = (int)xrb, iyr = (int)yrb;
      float vlt = xpb[(ixl * WP + iyl) * Cc + lane];
      float vrb = xpb[(ixr * WP + iyr) * Cc + lane];
      float vlb = xpb[(ixl * WP + iyr) * Cc + lane];
      float vrt = xpb[(ixr * WP + iyl) * Cc + lane];
      float xw = (glt*vlt + grb*vrb + glb*vlb + grt*vrt) * mn;
      sh[pl][n * 64 + lane] = f2bf(xw);   // k = n*64 + ci
    }
  }
  __syncthreads();

  int mrow = lane & 15;          // A row (co in tile) == B col (pixel)
  int quad = lane >> 4;
  int cotile = wave * 16;
  float4v acc = {0.f, 0.f, 0.f, 0.f};
  for (int ks = 0; ks < 18; ++ks) {
    short8 a = *reinterpret_cast<const short8*>(
        wt + (cotile + mrow) * 576 + ks * 32 + quad * 8);
    short8 bfr = *reinterpret_cast<const short8*>(
        &sh[mrow][ks * 32 + quad * 8]);
    acc = __builtin_amdgcn_mfma_f32_16x16x32_bf16(a, bfr, acc, 0, 0, 0);
  }
  #pragma unroll
  for (int r = 0; r < 4; ++r) {
    int co = cotile + quad * 4 + r;
    out[((b * Cc + co) * Hh + h) * Wd + w0 + mrow] = acc[r];
  }
}

// ---------------------------------------------------------------------------
// Fallback warp kernel (R9-verified scalar path; no d_ws needed).
// ---------------------------------------------------------------------------
__global__ __launch_bounds__(256)
void k_warp_s(const float* __restrict__ x,
              const float* __restrict__ off_f,
              const float* __restrict__ wg,
              const float* __restrict__ bg,
              const float* __restrict__ wc,
              float* __restrict__ out) {
  __shared__ float mred[4][Np][64];
  __shared__ float mval[4][Np];
  __shared__ float xwv[4][Np][64];
  int lane = threadIdx.x & 63;
  int wave = threadIdx.x >> 6;
  int p = blockIdx.x * 4 + wave;
  int b = p >> 14;
  int rem = p & 16383;
  int h = rem >> 7;
  int w = rem & 127;
  const float* xc = x + (b*Cc + lane) * HW;

  float part[Np];
  #pragma unroll
  for (int n = 0; n < Np; ++n) part[n] = 0.f;
  #pragma unroll
  for (int kh = 0; kh < 3; ++kh) {
    int hh = h + kh - 1;
    if ((unsigned)hh >= (unsigned)Hh) continue;
    #pragma unroll
    for (int kw = 0; kw < 3; ++kw) {
      int ww = w + kw - 1;
      if ((unsigned)ww >= (unsigned)Wd) continue;
      float v = xc[hh*Wd + ww];
      #pragma unroll
      for (int n = 0; n < Np; ++n)
        part[n] += v * wg[(n*Cc + lane)*9 + kh*3 + kw];
    }
  }
  #pragma unroll
  for (int n = 0; n < Np; ++n) mred[wave][n][lane] = part[n];
  __syncthreads();
  if (lane < Np) {
    float s = bg[lane];
    for (int c = 0; c < Cc; ++c) s += mred[wave][lane][c];
    mval[wave][lane] = 1.f / (1.f + expf(-s));
  }
  __syncthreads();

  const float* offb = off_f + b * MHc * HW;
  int sp = h * Wd + w;
  #pragma unroll
  for (int n = 0; n < Np; ++n) {
    float ox = offb[n * HW + sp];
    float oy = offb[(9 + n) * HW + sp];
    float px = (float)(h + 1) + (float)(n / 3 - 1) + ox;
    float py = (float)(w + 1) + (float)(n % 3 - 1) + oy;
    float fxq = floorf(px), fyq = floorf(py);
    float xlt = fminf(fmaxf(fxq,       0.f), 129.f);
    float ylt = fminf(fmaxf(fyq,       0.f), 129.f);
    float xrb = fminf(fmaxf(fxq + 1.f, 0.f), 129.f);
    float yrb = fminf(fmaxf(fyq + 1.f, 0.f), 129.f);
    float pxc = fminf(fmaxf(px, 0.f), 129.f);
    float pyc = fminf(fmaxf(py, 0.f), 129.f);
    float glt = (1.f + xlt - pxc) * (1.f + ylt - pyc);
    float grb = (1.f - xrb + pxc) * (1.f - yrb + pyc);
    float glb = (1.f + xlt - pxc) * (1.f - yrb + pyc);
    float grt = (1.f - xrb + pxc) * (1.f + ylt - pyc);
    int ixl = (int)xlt, iyl = (int)ylt, ixr = (int)xrb, iyr = (int)yrb;
    float vlt = 0.f, vrb = 0.f, vlb = 0.f, vrt = 0.f;
    if (ixl >= 1 && ixl <= Hh && iyl >= 1 && iyl <= Wd) vlt = xc[(ixl-1)*Wd + (iyl-1)];
    if (ixr >= 1 && ixr <= Hh && iyr >= 1 && iyr <= Wd) vrb = xc[(ixr-1)*Wd + (iyr-1)];
    if (ixl >= 1 && ixl <= Hh && iyr >= 1 && iyr <= Wd) vlb = xc[(ixl-1)*Wd + (iyr-1)];
    if (ixr >= 1 && ixr <= Hh && iyl >= 1 && iyl <= Wd) vrt = xc[(ixr-1)*Wd + (iyl-1)];
    xwv[wave][n][lane] = (glt*vlt + grb*vrb + glb*vlb + grt*vrt) * mval[wave][n];
  }
  __syncthreads();

  float acc = 0.f;
  for (int c = 0; c < Cc; ++c) {
    #pragma unroll
    for (int n = 0; n < Np; ++n)
      acc += xwv[wave][n][c] * wc[(lane*Cc + c)*9 + n];
  }
  out[(b*Cc + lane)*HW + h*Wd + w] = acc;
}

// ---------------------------------------------------------------------------
extern "C" void kernel_launch(void* const* d_in, const int* in_sizes, int n_in,
                              void* d_out, int out_size, void* d_ws, size_t ws_size,
                              hipStream_t stream) {
  (void)in_sizes; (void)n_in; (void)out_size;
  const float* x_t   = (const float*)d_in[0];
  const float* po    = (const float*)d_in[1];
  const float* mean  = (const float*)d_in[2];
  const float* upd_w = (const float*)d_in[3];
  const float* upd_b = (const float*)d_in[4];
  const float* rst_w = (const float*)d_in[5];
  const float* rst_b = (const float*)d_in[6];
  const float* out_w = (const float*)d_in[7];
  const float* out_b = (const float*)d_in[8];
  const float* wg_w  = (const float*)d_in[9];
  const float* wg_b  = (const float*)d_in[10];
  const float* wcw   = (const float*)d_in[11];

  float* out_x   = (float*)d_out;            // [4,64,128,128]
  float* out_off = out_x + 4194304;          // [4,18,128,128]
  float* out_mn  = out_off + 1179648;        // [4,18,128,128]

  // u/ro scratch inside out_x region (overwritten last by warp kernel)
  float* u_scr  = out_x;
  float* ro_scr = out_x + 1179648;

  // ws layout: xpad f32 17,305,600 B | wt_bf 73,728 B | m_ws 2,359,296 B
  const size_t WS_NEED = 19738624;
  char* ws = (char*)d_ws;
  float* xpad            = (float*)(ws + 0);
  __hip_bfloat16* wt_bf  = (__hip_bfloat16*)(ws + 17305600);
  float* m_ws            = (float*)(ws + 17379328);

  hipLaunchKernelGGL(k_convAB, dim3(4608), dim3(256), 0, stream,
                     x_t, po, upd_w, upd_b, rst_w, rst_b, u_scr, ro_scr);
  hipLaunchKernelGGL(k_convC,  dim3(4608), dim3(256), 0, stream,
                     x_t, po, mean, out_w, out_b, u_scr, ro_scr,
                     out_off, out_mn);

  if (ws_size >= WS_NEED) {
    hipLaunchKernelGGL(k_zero,   dim3(16900), dim3(256), 0, stream, xpad);
    hipLaunchKernelGGL(k_prep,   dim3(4096),  dim3(256), 0, stream, x_t, xpad);
    hipLaunchKernelGGL(k_wt,     dim3(144),   dim3(256), 0, stream, wcw, wt_bf);
    hipLaunchKernelGGL(k_convM,  dim3(2304),  dim3(256), 0, stream,
                       x_t, wg_w, wg_b, m_ws);
    hipLaunchKernelGGL(k_warp_m, dim3(4096),  dim3(256), 0, stream,
                       xpad, out_off, m_ws, wt_bf, out_x);
  } else {
    hipLaunchKernelGGL(k_warp_s, dim3(16384), dim3(256), 0, stream,
                       x_t, out_off, wg_w, wg_b, wcw, out_x);
  }
}

// Round 11
// 278.839 us; speedup vs baseline: 20.0822x; 3.7120x over previous
//
#include <hip/hip_runtime.h>
#include <hip/hip_bf16.h>
#include <math.h>

// Problem constants
#define Bn  4
#define Cc  64
#define MHc 18
#define Hh  128
#define Wd  128
#define HW  (Hh*Wd)
#define Np  9
#define HP  130
#define WP  130
#define XPE (HP*WP*Cc)     // xpad elems per batch (bf16): 1,081,600
#define PPE (HP*WP*32)     // popad/ropad elems per batch: 540,800
#define KX  576            // x-tap K (9*64)
#define KP  288            // po-tap K (9*32)
#define KT  (KX+KP)        // 864 total K, 27 MFMA steps

typedef __attribute__((ext_vector_type(8))) short short8;
typedef __attribute__((ext_vector_type(4))) float float4v;

__device__ __forceinline__ float bf2f(__hip_bfloat16 x) { return __bfloat162float(x); }
__device__ __forceinline__ __hip_bfloat16 f2bf(float x) { return __float2bfloat16(x); }
__device__ __forceinline__ float sigm(float x) { return 1.f / (1.f + expf(-x)); }

// ---------------------------------------------------------------------------
// K1: x [B,C,H,W] f32 -> xpad [B,130,130,64] bf16 (interior; borders pre-0)
// ---------------------------------------------------------------------------
__global__ __launch_bounds__(256)
void k_prepx(const float* __restrict__ x, __hip_bfloat16* __restrict__ xp) {
  __shared__ float tile[16][65];
  int blk = blockIdx.x;
  int wtile = blk & 7;
  int h = (blk >> 3) & 127;
  int b = blk >> 10;
  int w0 = wtile * 16;
  int t = threadIdx.x;
  int wa = t & 15, cq = t >> 4;
  #pragma unroll
  for (int j = 0; j < 4; ++j) {
    int c = cq * 4 + j;
    tile[wa][c] = x[(b*Cc + c)*HW + h*Wd + w0 + wa];
  }
  __syncthreads();
  int cb = t & 63, wq = t >> 6;
  #pragma unroll
  for (int j = 0; j < 4; ++j) {
    int w = wq * 4 + j;
    xp[b*XPE + ((h+1)*WP + (w0 + w + 1))*Cc + cb] = f2bf(tile[w][cb]);
  }
}

// ---------------------------------------------------------------------------
// K2: po [B,18,H,W] f32 -> popad [B,130,130,32] bf16 (ch 18..31 stay 0)
// ---------------------------------------------------------------------------
__global__ __launch_bounds__(256)
void k_prepp(const float* __restrict__ po, __hip_bfloat16* __restrict__ pp) {
  int blk = blockIdx.x;           // b*128 + h
  int h = blk & 127;
  int b = blk >> 7;
  int t = threadIdx.x;
  int w = t & 127;
  int half = t >> 7;              // 0/1 -> ch 0..8 / 9..17
  for (int j = 0; j < 9; ++j) {
    int ch = half * 9 + j;
    float v = po[(b*MHc + ch)*HW + h*Wd + w];
    pp[b*PPE + ((h+1)*WP + (w+1))*32 + ch] = f2bf(v);
  }
}

// ---------------------------------------------------------------------------
// K3: combined gate weights wAll[64][864] bf16.
// rows 0-17 upd, 18-35 rst, 36-53 out_w(x-part), 54-62 wg, 63 zero.
// k<576: k=n*64+ci (x taps); k>=576: k=576+n*32+jc (po taps, jc<18 real).
// ---------------------------------------------------------------------------
__global__ void k_wall(const float* __restrict__ upd_w,
                       const float* __restrict__ rst_w,
                       const float* __restrict__ out_w,
                       const float* __restrict__ wg_w,
                       __hip_bfloat16* __restrict__ wall) {
  int idx = blockIdx.x * 256 + threadIdx.x;
  if (idx >= 64 * KT) return;
  int k  = idx % KT;
  int gr = idx / KT;
  float v = 0.f;
  if (k < KX) {
    int n = k >> 6, ci = k & 63;
    if      (gr < 18) v = upd_w[(gr*(Cc+MHc) + ci)*9 + n];
    else if (gr < 36) v = rst_w[((gr-18)*(Cc+MHc) + ci)*9 + n];
    else if (gr < 54) v = out_w[((gr-36)*(Cc+MHc) + ci)*9 + n];
    else if (gr < 63) v = wg_w[((gr-54)*Cc + ci)*9 + n];
  } else {
    int kk = k - KX;
    int n = kk >> 5, jc = kk & 31;
    if (jc < 18) {
      if      (gr < 18) v = upd_w[(gr*(Cc+MHc) + Cc + jc)*9 + n];
      else if (gr < 36) v = rst_w[((gr-18)*(Cc+MHc) + Cc + jc)*9 + n];
    }
  }
  wall[idx] = f2bf(v);
}

// K3b: stage-2 weights wAll2[32][288] bf16 (ro taps of out_w; rows>=18 zero)
__global__ void k_wall2(const float* __restrict__ out_w,
                        __hip_bfloat16* __restrict__ w2) {
  int idx = blockIdx.x * 256 + threadIdx.x;
  if (idx >= 32 * KP) return;
  int k  = idx % KP;
  int oc = idx / KP;
  int n = k >> 5, jc = k & 31;
  float v = (oc < 18 && jc < 18) ? out_w[(oc*(Cc+MHc) + Cc + jc)*9 + n] : 0.f;
  w2[idx] = f2bf(v);
}

// K3c: warp conv weights wt[co][k], k = n*64+ci (for k_warp_m)
__global__ void k_wt(const float* __restrict__ w,
                     __hip_bfloat16* __restrict__ wt) {
  int idx = blockIdx.x * 256 + threadIdx.x;
  if (idx >= Cc * Cc * Np) return;
  int k  = idx % 576;
  int co = idx / 576;
  int n  = k >> 6;
  int ci = k & 63;
  wt[idx] = f2bf(w[(co*Cc + ci)*9 + n]);
}

// ---------------------------------------------------------------------------
// K4: all-gates MFMA GEMM. Block = (b,h,16px), 4 waves; M=64 rows x K=864.
// Epilogue: u (f32 scr), ro=r*po (-> ropad bf16 CL), cx=acc+out_b (f32 scr),
// m (-> m_bf bf16).
// ---------------------------------------------------------------------------
__global__ __launch_bounds__(256)
void k_gates(const __hip_bfloat16* __restrict__ xpad,
             const __hip_bfloat16* __restrict__ popad,
             const __hip_bfloat16* __restrict__ wall,
             const float* __restrict__ po,
             const float* __restrict__ upd_b,
             const float* __restrict__ rst_b,
             const float* __restrict__ out_b,
             const float* __restrict__ wg_b,
             float* __restrict__ u_scr,
             float* __restrict__ cx_scr,
             __hip_bfloat16* __restrict__ ropad,
             __hip_bfloat16* __restrict__ m_bf) {
  __shared__ __align__(16) __hip_bfloat16 sh[16][KT + 8];
  int blk = blockIdx.x;
  int wtile = blk & 7;
  int h = (blk >> 3) & 127;
  int b = blk >> 10;
  int w0 = wtile * 16;
  int lane = threadIdx.x & 63;
  int wave = threadIdx.x >> 6;

  const __hip_bfloat16* xpb = xpad + b * XPE;
  const __hip_bfloat16* ppb = popad + b * PPE;
  int c32 = lane & 31, tsel = lane >> 5;

  for (int t = 0; t < 4; ++t) {
    int pl = wave * 4 + t;
    int wp = w0 + pl;
    #pragma unroll
    for (int n = 0; n < 9; ++n)
      sh[pl][n*64 + lane] = xpb[((h + n/3)*WP + wp + n%3)*Cc + lane];
    #pragma unroll
    for (int nb = 0; nb < 9; nb += 2) {
      int n = nb + tsel;
      if (n < 9)
        sh[pl][KX + n*32 + c32] = ppb[((h + n/3)*WP + wp + n%3)*32 + c32];
    }
  }
  __syncthreads();

  int mrow = lane & 15;
  int quad = lane >> 4;
  int cotile = wave * 16;
  float4v acc = {0.f, 0.f, 0.f, 0.f};
  for (int ks = 0; ks < KT/32; ++ks) {
    short8 a = *reinterpret_cast<const short8*>(
        wall + (cotile + mrow) * KT + ks * 32 + quad * 8);
    short8 bfr = *reinterpret_cast<const short8*>(
        &sh[mrow][ks * 32 + quad * 8]);
    acc = __builtin_amdgcn_mfma_f32_16x16x32_bf16(a, bfr, acc, 0, 0, 0);
  }

  int sp = h * Wd + w0 + mrow;   // this lane's pixel
  #pragma unroll
  for (int r = 0; r < 4; ++r) {
    int gr = cotile + quad * 4 + r;
    float v = acc[r];
    if (gr < 18) {
      u_scr[(b*MHc + gr)*HW + sp] = sigm(v + upd_b[gr]);
    } else if (gr < 36) {
      int oc = gr - 18;
      float rr = sigm(v + rst_b[oc]);
      float ro = rr * po[(b*MHc + oc)*HW + sp];
      ropad[b*PPE + ((h+1)*WP + (w0 + mrow + 1))*32 + oc] = f2bf(ro);
    } else if (gr < 54) {
      int oc = gr - 36;
      cx_scr[(b*MHc + oc)*HW + sp] = v + out_b[oc];
    } else if (gr < 63) {
      int nn = gr - 54;
      m_bf[(b*Np + nn)*HW + sp] = f2bf(sigm(v + wg_b[nn]));
    }
  }
}

// ---------------------------------------------------------------------------
// K5: stage-2 GEMM (ro taps, K=288, M=18) + offset/mean fusion.
// Block = (b,h,32px), 4 waves: wave = pxhalf*2 + rowtile.
// ---------------------------------------------------------------------------
__global__ __launch_bounds__(256)
void k_gemm2(const __hip_bfloat16* __restrict__ ropad,
             const __hip_bfloat16* __restrict__ w2,
             const float* __restrict__ po,
             const float* __restrict__ mean,
             const float* __restrict__ u_scr,
             const float* __restrict__ cx_scr,
             float* __restrict__ out_off,
             float* __restrict__ out_mn) {
  __shared__ __align__(16) __hip_bfloat16 sh[32][KP + 8];
  int blk = blockIdx.x;
  int wtile = blk & 3;
  int h = (blk >> 2) & 127;
  int b = blk >> 9;
  int w0 = wtile * 32;
  int lane = threadIdx.x & 63;
  int wave = threadIdx.x >> 6;

  const __hip_bfloat16* rpb = ropad + b * PPE;
  int c32 = lane & 31, tsel = lane >> 5;
  for (int t = 0; t < 8; ++t) {
    int pl = wave * 8 + t;
    int wp = w0 + pl;
    #pragma unroll
    for (int nb = 0; nb < 9; nb += 2) {
      int n = nb + tsel;
      if (n < 9)
        sh[pl][n*32 + c32] = rpb[((h + n/3)*WP + wp + n%3)*32 + c32];
    }
  }
  __syncthreads();

  int mrow = lane & 15;
  int quad = lane >> 4;
  int rowtile = wave & 1;        // 0: rows 0-15, 1: rows 16-31 (only 16-17 real)
  int pxhalf  = wave >> 1;       // 0: px 0-15, 1: px 16-31
  float4v acc = {0.f, 0.f, 0.f, 0.f};
  for (int ks = 0; ks < KP/32; ++ks) {
    short8 a = *reinterpret_cast<const short8*>(
        w2 + (rowtile*16 + mrow) * KP + ks * 32 + quad * 8);
    short8 bfr = *reinterpret_cast<const short8*>(
        &sh[pxhalf*16 + mrow][ks * 32 + quad * 8]);
    acc = __builtin_amdgcn_mfma_f32_16x16x32_bf16(a, bfr, acc, 0, 0, 0);
  }

  int sp = h * Wd + w0 + pxhalf*16 + mrow;
  #pragma unroll
  for (int r = 0; r < 4; ++r) {
    int gr = rowtile*16 + quad * 4 + r;
    if (gr < 18) {
      int gi = (b*MHc + gr)*HW + sp;
      float cand = tanhf(cx_scr[gi] + acc[r]);
      float u = u_scr[gi];
      float p = po[gi];
      float mn = 0.5f * (mean[gi] + p);
      out_off[gi] = p * (1.f - u) + cand * u + mn;
      out_mn[gi]  = mn;
    }
  }
}

// ---------------------------------------------------------------------------
// K6: deformable gather (bf16 channels-last) + MFMA 64x576 GEMM (verified).
// ---------------------------------------------------------------------------
__global__ __launch_bounds__(256)
void k_warp_m(const __hip_bfloat16* __restrict__ xpad,
              const float* __restrict__ off_f,
              const __hip_bfloat16* __restrict__ m_bf,
              const __hip_bfloat16* __restrict__ wt,
              float* __restrict__ out) {
  __shared__ __align__(16) __hip_bfloat16 sh[16][584];
  int blk = blockIdx.x;
  int wtile = blk & 7;
  int h = (blk >> 3) & 127;
  int b = blk >> 10;
  int w0 = wtile * 16;
  int lane = threadIdx.x & 63;
  int wave = threadIdx.x >> 6;

  const __hip_bfloat16* xpb = xpad + b * XPE;
  const float* offb = off_f + b * MHc * HW;
  const __hip_bfloat16* mb = m_bf + b * Np * HW;

  for (int t = 0; t < 4; ++t) {
    int pl = wave * 4 + t;
    int wp = w0 + pl;
    int sp = h * Wd + wp;
    #pragma unroll
    for (int n = 0; n < Np; ++n) {
      float ox = offb[n * HW + sp];
      float oy = offb[(9 + n) * HW + sp];
      float mn = bf2f(mb[n * HW + sp]);
      float px = (float)(h + 1) + (float)(n / 3 - 1) + ox;
      float py = (float)(wp + 1) + (float)(n % 3 - 1) + oy;
      float fx = floorf(px), fy = floorf(py);
      float xlt = fminf(fmaxf(fx,       0.f), 129.f);
      float ylt = fminf(fmaxf(fy,       0.f), 129.f);
      float xrb = fminf(fmaxf(fx + 1.f, 0.f), 129.f);
      float yrb = fminf(fmaxf(fy + 1.f, 0.f), 129.f);
      float pxc = fminf(fmaxf(px, 0.f), 129.f);
      float pyc = fminf(fmaxf(py, 0.f), 129.f);
      float glt = (1.f + xlt - pxc) * (1.f + ylt - pyc);
      float grb = (1.f - xrb + pxc) * (1.f - yrb + pyc);
      float glb = (1.f + xlt - pxc) * (1.f - yrb + pyc);
      float grt = (1.f - xrb + pxc) * (1.f + ylt - pyc);
      int ixl = (int)xlt, iyl = (int)ylt, ixr = (int)xrb, iyr = (int)yrb;
      float vlt = bf2f(xpb[(ixl * WP + iyl) * Cc + lane]);
      float vrb = bf2f(xpb[(ixr * WP + iyr) * Cc + lane]);
      float vlb = bf2f(xpb[(ixl * WP + iyr) * Cc + lane]);
      float vrt = bf2f(xpb[(ixr * WP + iyl) * Cc + lane]);
      float xw = (glt*vlt + grb*vrb + glb*vlb + grt*vrt) * mn;
      sh[pl][n * 64 + lane] = f2bf(xw);
    }
  }
  __syncthreads();

  int mrow = lane & 15;
  int quad = lane >> 4;
  int cotile = wave * 16;
  float4v acc = {0.f, 0.f, 0.f, 0.f};
  for (int ks = 0; ks < 18; ++ks) {
    short8 a = *reinterpret_cast<const short8*>(
        wt + (cotile + mrow) * 576 + ks * 32 + quad * 8);
    short8 bfr = *reinterpret_cast<const short8*>(
        &sh[mrow][ks * 32 + quad * 8]);
    acc = __builtin_amdgcn_mfma_f32_16x16x32_bf16(a, bfr, acc, 0, 0, 0);
  }
  #pragma unroll
  for (int r = 0; r < 4; ++r) {
    int co = cotile + quad * 4 + r;
    out[((b * Cc + co) * Hh + h) * Wd + w0 + mrow] = acc[r];
  }
}

// ---------------------------------------------------------------------------
// Fallback (R9-verified scalar pipeline; zero ws) -------------------------------
__global__ void f_convAB(const float* __restrict__ x, const float* __restrict__ po,
                         const float* __restrict__ wA, const float* __restrict__ bA,
                         const float* __restrict__ wB, const float* __restrict__ bB,
                         float* __restrict__ u_scr, float* __restrict__ ro_scr) {
  int idx = blockIdx.x * 256 + threadIdx.x;
  if (idx >= Bn * MHc * HW) return;
  int w = idx & 127, h = (idx >> 7) & 127, oc = (idx >> 14) % MHc, b = idx / (MHc*HW);
  float accA = bA[oc], accB = bB[oc];
  const float* xb = x + b*Cc*HW; const float* pb = po + b*MHc*HW;
  for (int ic = 0; ic < Cc + MHc; ++ic) {
    const float* src = (ic < Cc) ? (xb + ic*HW) : (pb + (ic-Cc)*HW);
    const float* wa = wA + (oc*(Cc+MHc)+ic)*9; const float* wb = wB + (oc*(Cc+MHc)+ic)*9;
    for (int kh = 0; kh < 3; ++kh) { int hh = h+kh-1; if ((unsigned)hh >= Hh) continue;
      for (int kw = 0; kw < 3; ++kw) { int ww = w+kw-1; if ((unsigned)ww >= Wd) continue;
        float v = src[hh*Wd+ww]; accA += v*wa[kh*3+kw]; accB += v*wb[kh*3+kw]; } }
  }
  u_scr[idx] = sigm(accA); ro_scr[idx] = sigm(accB) * pb[oc*HW + h*Wd + w];
}
__global__ void f_convC(const float* __restrict__ x, const float* __restrict__ po,
                        const float* __restrict__ mean, const float* __restrict__ wC,
                        const float* __restrict__ bC, const float* __restrict__ u_scr,
                        const float* __restrict__ ro_scr, float* __restrict__ out_off,
                        float* __restrict__ out_mean) {
  int idx = blockIdx.x * 256 + threadIdx.x;
  if (idx >= Bn * MHc * HW) return;
  int w = idx & 127, h = (idx >> 7) & 127, oc = (idx >> 14) % MHc, b = idx / (MHc*HW);
  float acc = bC[oc];
  const float* xb = x + b*Cc*HW; const float* rb = ro_scr + b*MHc*HW;
  for (int ic = 0; ic < Cc + MHc; ++ic) {
    const float* src = (ic < Cc) ? (xb + ic*HW) : (rb + (ic-Cc)*HW);
    const float* wv = wC + (oc*(Cc+MHc)+ic)*9;
    for (int kh = 0; kh < 3; ++kh) { int hh = h+kh-1; if ((unsigned)hh >= Hh) continue;
      for (int kw = 0; kw < 3; ++kw) { int ww = w+kw-1; if ((unsigned)ww >= Wd) continue;
        acc += src[hh*Wd+ww]*wv[kh*3+kw]; } }
  }
  float cand = tanhf(acc); float u = u_scr[idx]; float p = po[idx];
  float mn = 0.5f*(mean[idx]+p);
  out_off[idx] = p*(1.f-u)+cand*u+mn; out_mean[idx] = mn;
}
__global__ __launch_bounds__(256)
void f_warp(const float* __restrict__ x, const float* __restrict__ off_f,
            const float* __restrict__ wg, const float* __restrict__ bg,
            const float* __restrict__ wc, float* __restrict__ out) {
  __shared__ float mred[4][Np][64]; __shared__ float mval[4][Np];
  __shared__ float xwv[4][Np][64];
  int lane = threadIdx.x & 63, wave = threadIdx.x >> 6;
  int p = blockIdx.x * 4 + wave;
  int b = p >> 14, rem = p & 16383, h = rem >> 7, w = rem & 127;
  const float* xc = x + (b*Cc + lane)*HW;
  float part[Np];
  for (int n = 0; n < Np; ++n) part[n] = 0.f;
  for (int kh = 0; kh < 3; ++kh) { int hh = h+kh-1; if ((unsigned)hh >= Hh) continue;
    for (int kw = 0; kw < 3; ++kw) { int ww = w+kw-1; if ((unsigned)ww >= Wd) continue;
      float v = xc[hh*Wd+ww];
      for (int n = 0; n < Np; ++n) part[n] += v*wg[(n*Cc+lane)*9+kh*3+kw]; } }
  for (int n = 0; n < Np; ++n) mred[wave][n][lane] = part[n];
  __syncthreads();
  if (lane < Np) { float s = bg[lane];
    for (int c = 0; c < Cc; ++c) s += mred[wave][lane][c];
    mval[wave][lane] = sigm(s); }
  __syncthreads();
  const float* offb = off_f + b*MHc*HW; int sp = h*Wd + w;
  for (int n = 0; n < Np; ++n) {
    float px = (float)(h+1) + (float)(n/3-1) + offb[n*HW+sp];
    float py = (float)(w+1) + (float)(n%3-1) + offb[(9+n)*HW+sp];
    float fxq = floorf(px), fyq = floorf(py);
    float xlt = fminf(fmaxf(fxq,0.f),129.f), ylt = fminf(fmaxf(fyq,0.f),129.f);
    float xrb = fminf(fmaxf(fxq+1.f,0.f),129.f), yrb = fminf(fmaxf(fyq+1.f,0.f),129.f);
    float pxc = fminf(fmaxf(px,0.f),129.f), pyc = fminf(fmaxf(py,0.f),129.f);
    float glt = (1.f+xlt-pxc)*(1.f+ylt-pyc), grb = (1.f-xrb+pxc)*(1.f-yrb+pyc);
    float glb = (1.f+xlt-pxc)*(1.f-yrb+pyc), grt = (1.f-xrb+pxc)*(1.f+ylt-pyc);
    int ixl=(int)xlt, iyl=(int)ylt, ixr=(int)xrb, iyr=(int)yrb;
    float vlt=0.f,vrb=0.f,vlb=0.f,vrt=0.f;
    if (ixl>=1&&ixl<=Hh&&iyl>=1&&iyl<=Wd) vlt = xc[(ixl-1)*Wd+(iyl-1)];
    if (ixr>=1&&ixr<=Hh&&iyr>=1&&iyr<=Wd) vrb = xc[(ixr-1)*Wd+(iyr-1)];
    if (ixl>=1&&ixl<=Hh&&iyr>=1&&iyr<=Wd) vlb = xc[(ixl-1)*Wd+(iyr-1)];
    if (ixr>=1&&ixr<=Hh&&iyl>=1&&iyl<=Wd) vrt = xc[(ixr-1)*Wd+(iyl-1)];
    xwv[wave][n][lane] = (glt*vlt+grb*vrb+glb*vlb+grt*vrt)*mval[wave][n];
  }
  __syncthreads();
  float acc = 0.f;
  for (int c = 0; c < Cc; ++c)
    for (int n = 0; n < Np; ++n)
      acc += xwv[wave][n][c]*wc[(lane*Cc+c)*9+n];
  out[(b*Cc+lane)*HW + h*Wd + w] = acc;
}

// ---------------------------------------------------------------------------
extern "C" void kernel_launch(void* const* d_in, const int* in_sizes, int n_in,
                              void* d_out, int out_size, void* d_ws, size_t ws_size,
                              hipStream_t stream) {
  (void)in_sizes; (void)n_in; (void)out_size;
  const float* x_t   = (const float*)d_in[0];
  const float* po    = (const float*)d_in[1];
  const float* mean  = (const float*)d_in[2];
  const float* upd_w = (const float*)d_in[3];
  const float* upd_b = (const float*)d_in[4];
  const float* rst_w = (const float*)d_in[5];
  const float* rst_b = (const float*)d_in[6];
  const float* out_w = (const float*)d_in[7];
  const float* out_b = (const float*)d_in[8];
  const float* wg_w  = (const float*)d_in[9];
  const float* wg_b  = (const float*)d_in[10];
  const float* wcw   = (const float*)d_in[11];

  float* out_x   = (float*)d_out;            // [4,64,128,128]
  float* out_off = out_x + 4194304;          // [4,18,128,128]
  float* out_mn  = out_off + 1179648;        // [4,18,128,128]

  // scratch inside out_x region (consumed before k_warp_m overwrites it)
  float* u_scr  = out_x;                     // 1,179,648 f32
  float* cx_scr = out_x + 1179648;           // 1,179,648 f32

  // ws layout (18,688,000 B total; ws_size >= 19,738,624 proven in R10)
  char* ws = (char*)d_ws;
  __hip_bfloat16* xpad  = (__hip_bfloat16*)(ws + 0);          //  8,652,800
  __hip_bfloat16* popad = (__hip_bfloat16*)(ws + 8652800);    //  4,326,400
  __hip_bfloat16* ropad = (__hip_bfloat16*)(ws + 12979200);   //  4,326,400
  __hip_bfloat16* wall  = (__hip_bfloat16*)(ws + 17305600);   //    110,592
  __hip_bfloat16* w2    = (__hip_bfloat16*)(ws + 17416192);   //     18,432
  __hip_bfloat16* wt_bf = (__hip_bfloat16*)(ws + 17434624);   //     73,728
  __hip_bfloat16* m_bf  = (__hip_bfloat16*)(ws + 17508352);   //  1,179,648
  const size_t WS_NEED = 18688000;

  if (ws_size >= WS_NEED) {
    hipMemsetAsync(d_ws, 0, 17305600, stream);   // xpad+popad+ropad zero
    hipLaunchKernelGGL(k_prepx, dim3(4096), dim3(256), 0, stream, x_t, xpad);
    hipLaunchKernelGGL(k_prepp, dim3(512),  dim3(256), 0, stream, po, popad);
    hipLaunchKernelGGL(k_wall,  dim3(216),  dim3(256), 0, stream,
                       upd_w, rst_w, out_w, wg_w, wall);
    hipLaunchKernelGGL(k_wall2, dim3(36),   dim3(256), 0, stream, out_w, w2);
    hipLaunchKernelGGL(k_wt,    dim3(144),  dim3(256), 0, stream, wcw, wt_bf);
    hipLaunchKernelGGL(k_gates, dim3(4096), dim3(256), 0, stream,
                       xpad, popad, wall, po, upd_b, rst_b, out_b, wg_b,
                       u_scr, cx_scr, ropad, m_bf);
    hipLaunchKernelGGL(k_gemm2, dim3(2048), dim3(256), 0, stream,
                       ropad, w2, po, mean, u_scr, cx_scr, out_off, out_mn);
    hipLaunchKernelGGL(k_warp_m, dim3(4096), dim3(256), 0, stream,
                       xpad, out_off, m_bf, wt_bf, out_x);
  } else {
    hipLaunchKernelGGL(f_convAB, dim3(4608), dim3(256), 0, stream,
                       x_t, po, upd_w, upd_b, rst_w, rst_b, u_scr, cx_scr);
    hipLaunchKernelGGL(f_convC,  dim3(4608), dim3(256), 0, stream,
                       x_t, po, mean, out_w, out_b, u_scr, cx_scr,
                       out_off, out_mn);
    hipLaunchKernelGGL(f_warp,   dim3(16384), dim3(256), 0, stream,
                       x_t, out_off, wg_w, wg_b, wcw, out_x);
  }
}

// Round 12
// 224.047 us; speedup vs baseline: 24.9935x; 1.2446x over previous
//
#include <hip/hip_runtime.h>
#include <hip/hip_bf16.h>
#include <math.h>

// Problem constants
#define Bn  4
#define Cc  64
#define MHc 18
#define Hh  128
#define Wd  128
#define HW  (Hh*Wd)
#define Np  9
#define HP  130
#define WP  130
#define XPE (HP*WP*Cc)     // xpad elems per batch (bf16): 1,081,600
#define PPE (HP*WP*32)     // popad/ropad elems per batch: 540,800
#define KX  576            // x-tap K (9*64)
#define KP  288            // po-tap K (9*32)
#define KT  (KX+KP)        // 864 total K, 27 MFMA steps

typedef __attribute__((ext_vector_type(8))) short short8;
typedef __attribute__((ext_vector_type(4))) float float4v;

__device__ __forceinline__ float bf2f(__hip_bfloat16 x) { return __bfloat162float(x); }
__device__ __forceinline__ __hip_bfloat16 f2bf(float x) { return __float2bfloat16(x); }
__device__ __forceinline__ float sigm(float x) { return 1.f / (1.f + expf(-x)); }

// ---------------------------------------------------------------------------
// K1: merged activation prep.
// blocks 0..4095:   x [B,C,H,W] f32 -> xpad [B,130,130,64] bf16 (interior)
// blocks 4096..4607: po -> popad [B,130,130,32] bf16 (ch 18..31 stay 0)
// ---------------------------------------------------------------------------
__global__ __launch_bounds__(256)
void k_prep(const float* __restrict__ x, const float* __restrict__ po,
            __hip_bfloat16* __restrict__ xp, __hip_bfloat16* __restrict__ pp) {
  __shared__ float tile[16][65];
  int blk = blockIdx.x;
  int t = threadIdx.x;
  if (blk < 4096) {
    int wtile = blk & 7;
    int h = (blk >> 3) & 127;
    int b = blk >> 10;
    int w0 = wtile * 16;
    int wa = t & 15, cq = t >> 4;
    #pragma unroll
    for (int j = 0; j < 4; ++j) {
      int c = cq * 4 + j;
      tile[wa][c] = x[(b*Cc + c)*HW + h*Wd + w0 + wa];
    }
    __syncthreads();
    int cb = t & 63, wq = t >> 6;
    #pragma unroll
    for (int j = 0; j < 4; ++j) {
      int w = wq * 4 + j;
      xp[b*XPE + ((h+1)*WP + (w0 + w + 1))*Cc + cb] = f2bf(tile[w][cb]);
    }
  } else {
    int pb = blk - 4096;            // b*128 + h
    int h = pb & 127;
    int b = pb >> 7;
    int w = t & 127;
    int half = t >> 7;
    for (int j = 0; j < 9; ++j) {
      int ch = half * 9 + j;
      float v = po[(b*MHc + ch)*HW + h*Wd + w];
      pp[b*PPE + ((h+1)*WP + (w+1))*32 + ch] = f2bf(v);
    }
  }
}

// ---------------------------------------------------------------------------
// K2: merged weight prep: wall[64][864] | w2[32][288] | wt[64][576] (bf16)
// ---------------------------------------------------------------------------
#define NW1 (64*KT)          // 55296
#define NW2 (32*KP)          // 9216
#define NW3 (Cc*Cc*Np)       // 36864
__global__ void k_wprep(const float* __restrict__ upd_w,
                        const float* __restrict__ rst_w,
                        const float* __restrict__ out_w,
                        const float* __restrict__ wg_w,
                        const float* __restrict__ wcw,
                        __hip_bfloat16* __restrict__ wall,
                        __hip_bfloat16* __restrict__ w2,
                        __hip_bfloat16* __restrict__ wt) {
  int idx = blockIdx.x * 256 + threadIdx.x;
  if (idx < NW1) {
    int k  = idx % KT;
    int gr = idx / KT;
    float v = 0.f;
    if (k < KX) {
      int n = k >> 6, ci = k & 63;
      if      (gr < 18) v = upd_w[(gr*(Cc+MHc) + ci)*9 + n];
      else if (gr < 36) v = rst_w[((gr-18)*(Cc+MHc) + ci)*9 + n];
      else if (gr < 54) v = out_w[((gr-36)*(Cc+MHc) + ci)*9 + n];
      else if (gr < 63) v = wg_w[((gr-54)*Cc + ci)*9 + n];
    } else {
      int kk = k - KX;
      int n = kk >> 5, jc = kk & 31;
      if (jc < 18) {
        if      (gr < 18) v = upd_w[(gr*(Cc+MHc) + Cc + jc)*9 + n];
        else if (gr < 36) v = rst_w[((gr-18)*(Cc+MHc) + Cc + jc)*9 + n];
      }
    }
    wall[idx] = f2bf(v);
  } else if (idx < NW1 + NW2) {
    int i2 = idx - NW1;
    int k  = i2 % KP;
    int oc = i2 / KP;
    int n = k >> 5, jc = k & 31;
    float v = (oc < 18 && jc < 18) ? out_w[(oc*(Cc+MHc) + Cc + jc)*9 + n] : 0.f;
    w2[i2] = f2bf(v);
  } else if (idx < NW1 + NW2 + NW3) {
    int i3 = idx - NW1 - NW2;
    int k  = i3 % 576;
    int co = i3 / 576;
    int n  = k >> 6;
    int ci = k & 63;
    wt[i3] = f2bf(wcw[(co*Cc + ci)*9 + n]);
  }
}

// ---------------------------------------------------------------------------
// K3: all-gates MFMA GEMM (M=64 x K=864 x 16px/block). Epilogue: u, ro, cx, m.
// ---------------------------------------------------------------------------
__global__ __launch_bounds__(256)
void k_gates(const __hip_bfloat16* __restrict__ xpad,
             const __hip_bfloat16* __restrict__ popad,
             const __hip_bfloat16* __restrict__ wall,
             const float* __restrict__ po,
             const float* __restrict__ upd_b,
             const float* __restrict__ rst_b,
             const float* __restrict__ out_b,
             const float* __restrict__ wg_b,
             float* __restrict__ u_scr,
             float* __restrict__ cx_scr,
             __hip_bfloat16* __restrict__ ropad,
             __hip_bfloat16* __restrict__ m_bf) {
  __shared__ __align__(16) __hip_bfloat16 sh[16][KT + 8];
  int blk = blockIdx.x;
  int wtile = blk & 7;
  int h = (blk >> 3) & 127;
  int b = blk >> 10;
  int w0 = wtile * 16;
  int lane = threadIdx.x & 63;
  int wave = threadIdx.x >> 6;

  const __hip_bfloat16* xpb = xpad + b * XPE;
  const __hip_bfloat16* ppb = popad + b * PPE;
  int c32 = lane & 31, tsel = lane >> 5;

  for (int t = 0; t < 4; ++t) {
    int pl = wave * 4 + t;
    int wp = w0 + pl;
    #pragma unroll
    for (int n = 0; n < 9; ++n)
      sh[pl][n*64 + lane] = xpb[((h + n/3)*WP + wp + n%3)*Cc + lane];
    #pragma unroll
    for (int nb = 0; nb < 9; nb += 2) {
      int n = nb + tsel;
      if (n < 9)
        sh[pl][KX + n*32 + c32] = ppb[((h + n/3)*WP + wp + n%3)*32 + c32];
    }
  }
  __syncthreads();

  int mrow = lane & 15;
  int quad = lane >> 4;
  int cotile = wave * 16;
  float4v acc = {0.f, 0.f, 0.f, 0.f};
  for (int ks = 0; ks < KT/32; ++ks) {
    short8 a = *reinterpret_cast<const short8*>(
        wall + (cotile + mrow) * KT + ks * 32 + quad * 8);
    short8 bfr = *reinterpret_cast<const short8*>(
        &sh[mrow][ks * 32 + quad * 8]);
    acc = __builtin_amdgcn_mfma_f32_16x16x32_bf16(a, bfr, acc, 0, 0, 0);
  }

  int sp = h * Wd + w0 + mrow;
  #pragma unroll
  for (int r = 0; r < 4; ++r) {
    int gr = cotile + quad * 4 + r;
    float v = acc[r];
    if (gr < 18) {
      u_scr[(b*MHc + gr)*HW + sp] = sigm(v + upd_b[gr]);
    } else if (gr < 36) {
      int oc = gr - 18;
      float rr = sigm(v + rst_b[oc]);
      float ro = rr * po[(b*MHc + oc)*HW + sp];
      ropad[b*PPE + ((h+1)*WP + (w0 + mrow + 1))*32 + oc] = f2bf(ro);
    } else if (gr < 54) {
      int oc = gr - 36;
      cx_scr[(b*MHc + oc)*HW + sp] = v + out_b[oc];
    } else if (gr < 63) {
      int nn = gr - 54;
      m_bf[(b*Np + nn)*HW + sp] = f2bf(sigm(v + wg_b[nn]));
    }
  }
}

// ---------------------------------------------------------------------------
// K4: stage-2 GEMM (ro taps, K=288, M=18) + offset/mean fusion.
// ---------------------------------------------------------------------------
__global__ __launch_bounds__(256)
void k_gemm2(const __hip_bfloat16* __restrict__ ropad,
             const __hip_bfloat16* __restrict__ w2,
             const float* __restrict__ po,
             const float* __restrict__ mean,
             const float* __restrict__ u_scr,
             const float* __restrict__ cx_scr,
             float* __restrict__ out_off,
             float* __restrict__ out_mn) {
  __shared__ __align__(16) __hip_bfloat16 sh[32][KP + 8];
  int blk = blockIdx.x;
  int wtile = blk & 3;
  int h = (blk >> 2) & 127;
  int b = blk >> 9;
  int w0 = wtile * 32;
  int lane = threadIdx.x & 63;
  int wave = threadIdx.x >> 6;

  const __hip_bfloat16* rpb = ropad + b * PPE;
  int c32 = lane & 31, tsel = lane >> 5;
  for (int t = 0; t < 8; ++t) {
    int pl = wave * 8 + t;
    int wp = w0 + pl;
    #pragma unroll
    for (int nb = 0; nb < 9; nb += 2) {
      int n = nb + tsel;
      if (n < 9)
        sh[pl][n*32 + c32] = rpb[((h + n/3)*WP + wp + n%3)*32 + c32];
    }
  }
  __syncthreads();

  int mrow = lane & 15;
  int quad = lane >> 4;
  int rowtile = wave & 1;
  int pxhalf  = wave >> 1;
  float4v acc = {0.f, 0.f, 0.f, 0.f};
  for (int ks = 0; ks < KP/32; ++ks) {
    short8 a = *reinterpret_cast<const short8*>(
        w2 + (rowtile*16 + mrow) * KP + ks * 32 + quad * 8);
    short8 bfr = *reinterpret_cast<const short8*>(
        &sh[pxhalf*16 + mrow][ks * 32 + quad * 8]);
    acc = __builtin_amdgcn_mfma_f32_16x16x32_bf16(a, bfr, acc, 0, 0, 0);
  }

  int sp = h * Wd + w0 + pxhalf*16 + mrow;
  #pragma unroll
  for (int r = 0; r < 4; ++r) {
    int gr = rowtile*16 + quad * 4 + r;
    if (gr < 18) {
      int gi = (b*MHc + gr)*HW + sp;
      float cand = tanhf(cx_scr[gi] + acc[r]);
      float u = u_scr[gi];
      float p = po[gi];
      float mn = 0.5f * (mean[gi] + p);
      out_off[gi] = p * (1.f - u) + cand * u + mn;
      out_mn[gi]  = mn;
    }
  }
}

// ---------------------------------------------------------------------------
// K5: deformable gather + MFMA 64x576 GEMM.
// NEW: bilinear weights & corner addresses precomputed once per (px,n) pair
// by 144 of the 256 threads (they're lane-invariant), stored in LDS; the
// gather loop is now ~15 VALU/iter instead of ~55.
// ---------------------------------------------------------------------------
__global__ __launch_bounds__(256)
void k_warp_m(const __hip_bfloat16* __restrict__ xpad,
              const float* __restrict__ off_f,
              const __hip_bfloat16* __restrict__ m_bf,
              const __hip_bfloat16* __restrict__ wt,
              float* __restrict__ out) {
  __shared__ __align__(16) __hip_bfloat16 sh[16][584];
  __shared__ __align__(16) float gw[144][4];
  __shared__ __align__(16) int   ga[144][4];
  int blk = blockIdx.x;
  int wtile = blk & 7;
  int h = (blk >> 3) & 127;
  int b = blk >> 10;
  int w0 = wtile * 16;
  int t = threadIdx.x;

  if (t < 144) {
    int px = t / 9, n = t % 9;
    int wp = w0 + px;
    int sp = h * Wd + wp;
    const float* offb = off_f + b * MHc * HW;
    float ox = offb[n * HW + sp];
    float oy = offb[(9 + n) * HW + sp];
    float mn = bf2f(m_bf[(b*Np + n) * HW + sp]);
    float px_ = (float)(h + 1) + (float)(n / 3 - 1) + ox;
    float py_ = (float)(wp + 1) + (float)(n % 3 - 1) + oy;
    float fx = floorf(px_), fy = floorf(py_);
    float xlt = fminf(fmaxf(fx,       0.f), 129.f);
    float ylt = fminf(fmaxf(fy,       0.f), 129.f);
    float xrb = fminf(fmaxf(fx + 1.f, 0.f), 129.f);
    float yrb = fminf(fmaxf(fy + 1.f, 0.f), 129.f);
    float pxc = fminf(fmaxf(px_, 0.f), 129.f);
    float pyc = fminf(fmaxf(py_, 0.f), 129.f);
    float glt = (1.f + xlt - pxc) * (1.f + ylt - pyc);
    float grb = (1.f - xrb + pxc) * (1.f - yrb + pyc);
    float glb = (1.f + xlt - pxc) * (1.f - yrb + pyc);
    float grt = (1.f - xrb + pxc) * (1.f + ylt - pyc);
    int ixl = (int)xlt, iyl = (int)ylt, ixr = (int)xrb, iyr = (int)yrb;
    gw[t][0] = glt * mn; gw[t][1] = grb * mn;
    gw[t][2] = glb * mn; gw[t][3] = grt * mn;
    ga[t][0] = (ixl * WP + iyl) * Cc; ga[t][1] = (ixr * WP + iyr) * Cc;
    ga[t][2] = (ixl * WP + iyr) * Cc; ga[t][3] = (ixr * WP + iyl) * Cc;
  }
  __syncthreads();

  int lane = t & 63;
  int wave = t >> 6;
  const __hip_bfloat16* xpb = xpad + b * XPE;
  for (int tt = 0; tt < 4; ++tt) {
    int pl = wave * 4 + tt;
    #pragma unroll
    for (int n = 0; n < Np; ++n) {
      int q = pl * 9 + n;
      float4v g = *reinterpret_cast<const float4v*>(gw[q]);   // LDS broadcast
      int a0 = ga[q][0], a1 = ga[q][1], a2 = ga[q][2], a3 = ga[q][3];
      float v0 = bf2f(xpb[a0 + lane]);
      float v1 = bf2f(xpb[a1 + lane]);
      float v2 = bf2f(xpb[a2 + lane]);
      float v3 = bf2f(xpb[a3 + lane]);
      sh[pl][n * 64 + lane] = f2bf(g.x*v0 + g.y*v1 + g.z*v2 + g.w*v3);
    }
  }
  __syncthreads();

  int mrow = lane & 15;
  int quad = lane >> 4;
  int cotile = wave * 16;
  float4v acc = {0.f, 0.f, 0.f, 0.f};
  for (int ks = 0; ks < 18; ++ks) {
    short8 a = *reinterpret_cast<const short8*>(
        wt + (cotile + mrow) * 576 + ks * 32 + quad * 8);
    short8 bfr = *reinterpret_cast<const short8*>(
        &sh[mrow][ks * 32 + quad * 8]);
    acc = __builtin_amdgcn_mfma_f32_16x16x32_bf16(a, bfr, acc, 0, 0, 0);
  }
  #pragma unroll
  for (int r = 0; r < 4; ++r) {
    int co = cotile + quad * 4 + r;
    out[((b * Cc + co) * Hh + h) * Wd + w0 + mrow] = acc[r];
  }
}

// ---------------------------------------------------------------------------
// Fallback (R9-verified scalar pipeline; zero ws)
// ---------------------------------------------------------------------------
__global__ void f_convAB(const float* __restrict__ x, const float* __restrict__ po,
                         const float* __restrict__ wA, const float* __restrict__ bA,
                         const float* __restrict__ wB, const float* __restrict__ bB,
                         float* __restrict__ u_scr, float* __restrict__ ro_scr) {
  int idx = blockIdx.x * 256 + threadIdx.x;
  if (idx >= Bn * MHc * HW) return;
  int w = idx & 127, h = (idx >> 7) & 127, oc = (idx >> 14) % MHc, b = idx / (MHc*HW);
  float accA = bA[oc], accB = bB[oc];
  const float* xb = x + b*Cc*HW; const float* pb = po + b*MHc*HW;
  for (int ic = 0; ic < Cc + MHc; ++ic) {
    const float* src = (ic < Cc) ? (xb + ic*HW) : (pb + (ic-Cc)*HW);
    const float* wa = wA + (oc*(Cc+MHc)+ic)*9; const float* wb = wB + (oc*(Cc+MHc)+ic)*9;
    for (int kh = 0; kh < 3; ++kh) { int hh = h+kh-1; if ((unsigned)hh >= Hh) continue;
      for (int kw = 0; kw < 3; ++kw) { int ww = w+kw-1; if ((unsigned)ww >= Wd) continue;
        float v = src[hh*Wd+ww]; accA += v*wa[kh*3+kw]; accB += v*wb[kh*3+kw]; } }
  }
  u_scr[idx] = sigm(accA); ro_scr[idx] = sigm(accB) * pb[oc*HW + h*Wd + w];
}
__global__ void f_convC(const float* __restrict__ x, const float* __restrict__ po,
                        const float* __restrict__ mean, const float* __restrict__ wC,
                        const float* __restrict__ bC, const float* __restrict__ u_scr,
                        const float* __restrict__ ro_scr, float* __restrict__ out_off,
                        float* __restrict__ out_mean) {
  int idx = blockIdx.x * 256 + threadIdx.x;
  if (idx >= Bn * MHc * HW) return;
  int w = idx & 127, h = (idx >> 7) & 127, oc = (idx >> 14) % MHc, b = idx / (MHc*HW);
  float acc = bC[oc];
  const float* xb = x + b*Cc*HW; const float* rb = ro_scr + b*MHc*HW;
  for (int ic = 0; ic < Cc + MHc; ++ic) {
    const float* src = (ic < Cc) ? (xb + ic*HW) : (rb + (ic-Cc)*HW);
    const float* wv = wC + (oc*(Cc+MHc)+ic)*9;
    for (int kh = 0; kh < 3; ++kh) { int hh = h+kh-1; if ((unsigned)hh >= Hh) continue;
      for (int kw = 0; kw < 3; ++kw) { int ww = w+kw-1; if ((unsigned)ww >= Wd) continue;
        acc += src[hh*Wd+ww]*wv[kh*3+kw]; } }
  }
  float cand = tanhf(acc); float u = u_scr[idx]; float p = po[idx];
  float mn = 0.5f*(mean[idx]+p);
  out_off[idx] = p*(1.f-u)+cand*u+mn; out_mean[idx] = mn;
}
__global__ __launch_bounds__(256)
void f_warp(const float* __restrict__ x, const float* __restrict__ off_f,
            const float* __restrict__ wg, const float* __restrict__ bg,
            const float* __restrict__ wc, float* __restrict__ out) {
  __shared__ float mred[4][Np][64]; __shared__ float mval[4][Np];
  __shared__ float xwv[4][Np][64];
  int lane = threadIdx.x & 63, wave = threadIdx.x >> 6;
  int p = blockIdx.x * 4 + wave;
  int b = p >> 14, rem = p & 16383, h = rem >> 7, w = rem & 127;
  const float* xc = x + (b*Cc + lane)*HW;
  float part[Np];
  for (int n = 0; n < Np; ++n) part[n] = 0.f;
  for (int kh = 0; kh < 3; ++kh) { int hh = h+kh-1; if ((unsigned)hh >= Hh) continue;
    for (int kw = 0; kw < 3; ++kw) { int ww = w+kw-1; if ((unsigned)ww >= Wd) continue;
      float v = xc[hh*Wd+ww];
      for (int n = 0; n < Np; ++n) part[n] += v*wg[(n*Cc+lane)*9+kh*3+kw]; } }
  for (int n = 0; n < Np; ++n) mred[wave][n][lane] = part[n];
  __syncthreads();
  if (lane < Np) { float s = bg[lane];
    for (int c = 0; c < Cc; ++c) s += mred[wave][lane][c];
    mval[wave][lane] = sigm(s); }
  __syncthreads();
  const float* offb = off_f + b*MHc*HW; int sp = h*Wd + w;
  for (int n = 0; n < Np; ++n) {
    float px = (float)(h+1) + (float)(n/3-1) + offb[n*HW+sp];
    float py = (float)(w+1) + (float)(n%3-1) + offb[(9+n)*HW+sp];
    float fxq = floorf(px), fyq = floorf(py);
    float xlt = fminf(fmaxf(fxq,0.f),129.f), ylt = fminf(fmaxf(fyq,0.f),129.f);
    float xrb = fminf(fmaxf(fxq+1.f,0.f),129.f), yrb = fminf(fmaxf(fyq+1.f,0.f),129.f);
    float pxc = fminf(fmaxf(px,0.f),129.f), pyc = fminf(fmaxf(py,0.f),129.f);
    float glt = (1.f+xlt-pxc)*(1.f+ylt-pyc), grb = (1.f-xrb+pxc)*(1.f-yrb+pyc);
    float glb = (1.f+xlt-pxc)*(1.f-yrb+pyc), grt = (1.f-xrb+pxc)*(1.f+ylt-pyc);
    int ixl=(int)xlt, iyl=(int)ylt, ixr=(int)xrb, iyr=(int)yrb;
    float vlt=0.f,vrb=0.f,vlb=0.f,vrt=0.f;
    if (ixl>=1&&ixl<=Hh&&iyl>=1&&iyl<=Wd) vlt = xc[(ixl-1)*Wd+(iyl-1)];
    if (ixr>=1&&ixr<=Hh&&iyr>=1&&iyr<=Wd) vrb = xc[(ixr-1)*Wd+(iyr-1)];
    if (ixl>=1&&ixl<=Hh&&iyr>=1&&iyr<=Wd) vlb = xc[(ixl-1)*Wd+(iyr-1)];
    if (ixr>=1&&ixr<=Hh&&iyl>=1&&iyl<=Wd) vrt = xc[(ixr-1)*Wd+(iyl-1)];
    xwv[wave][n][lane] = (glt*vlt+grb*vrb+glb*vlb+grt*vrt)*mval[wave][n];
  }
  __syncthreads();
  float acc = 0.f;
  for (int c = 0; c < Cc; ++c)
    for (int n = 0; n < Np; ++n)
      acc += xwv[wave][n][c]*wc[(lane*Cc+c)*9+n];
  out[(b*Cc+lane)*HW + h*Wd + w] = acc;
}

// ---------------------------------------------------------------------------
extern "C" void kernel_launch(void* const* d_in, const int* in_sizes, int n_in,
                              void* d_out, int out_size, void* d_ws, size_t ws_size,
                              hipStream_t stream) {
  (void)in_sizes; (void)n_in; (void)out_size;
  const float* x_t   = (const float*)d_in[0];
  const float* po    = (const float*)d_in[1];
  const float* mean  = (const float*)d_in[2];
  const float* upd_w = (const float*)d_in[3];
  const float* upd_b = (const float*)d_in[4];
  const float* rst_w = (const float*)d_in[5];
  const float* rst_b = (const float*)d_in[6];
  const float* out_w = (const float*)d_in[7];
  const float* out_b = (const float*)d_in[8];
  const float* wg_w  = (const float*)d_in[9];
  const float* wg_b  = (const float*)d_in[10];
  const float* wcw   = (const float*)d_in[11];

  float* out_x   = (float*)d_out;            // [4,64,128,128]
  float* out_off = out_x + 4194304;          // [4,18,128,128]
  float* out_mn  = out_off + 1179648;        // [4,18,128,128]

  float* u_scr  = out_x;                     // scratch in out_x region
  float* cx_scr = out_x + 1179648;

  char* ws = (char*)d_ws;
  __hip_bfloat16* xpad  = (__hip_bfloat16*)(ws + 0);          //  8,652,800
  __hip_bfloat16* popad = (__hip_bfloat16*)(ws + 8652800);    //  4,326,400
  __hip_bfloat16* ropad = (__hip_bfloat16*)(ws + 12979200);   //  4,326,400
  __hip_bfloat16* wall  = (__hip_bfloat16*)(ws + 17305600);   //    110,592
  __hip_bfloat16* w2    = (__hip_bfloat16*)(ws + 17416192);   //     18,432
  __hip_bfloat16* wt_bf = (__hip_bfloat16*)(ws + 17434624);   //     73,728
  __hip_bfloat16* m_bf  = (__hip_bfloat16*)(ws + 17508352);   //  1,179,648
  const size_t WS_NEED = 18688000;

  if (ws_size >= WS_NEED) {
    hipMemsetAsync(d_ws, 0, 17305600, stream);   // xpad+popad+ropad zero
    hipLaunchKernelGGL(k_prep,  dim3(4608), dim3(256), 0, stream,
                       x_t, po, xpad, popad);
    hipLaunchKernelGGL(k_wprep, dim3(396),  dim3(256), 0, stream,
                       upd_w, rst_w, out_w, wg_w, wcw, wall, w2, wt_bf);
    hipLaunchKernelGGL(k_gates, dim3(4096), dim3(256), 0, stream,
                       xpad, popad, wall, po, upd_b, rst_b, out_b, wg_b,
                       u_scr, cx_scr, ropad, m_bf);
    hipLaunchKernelGGL(k_gemm2, dim3(2048), dim3(256), 0, stream,
                       ropad, w2, po, mean, u_scr, cx_scr, out_off, out_mn);
    hipLaunchKernelGGL(k_warp_m, dim3(4096), dim3(256), 0, stream,
                       xpad, out_off, m_bf, wt_bf, out_x);
  } else {
    hipLaunchKernelGGL(f_convAB, dim3(4608), dim3(256), 0, stream,
                       x_t, po, upd_w, upd_b, rst_w, rst_b, u_scr, cx_scr);
    hipLaunchKernelGGL(f_convC,  dim3(4608), dim3(256), 0, stream,
                       x_t, po, mean, out_w, out_b, u_scr, cx_scr,
                       out_off, out_mn);
    hipLaunchKernelGGL(f_warp,   dim3(16384), dim3(256), 0, stream,
                       x_t, out_off, wg_w, wg_b, wcw, out_x);
  }
}

// Round 13
// 215.995 us; speedup vs baseline: 25.9252x; 1.0373x over previous
//
#include <hip/hip_runtime.h>
#include <hip/hip_bf16.h>
#include <math.h>

// Problem constants
#define Bn  4
#define Cc  64
#define MHc 18
#define Hh  128
#define Wd  128
#define HW  (Hh*Wd)
#define Np  9
#define HP  130
#define WP  130
#define XPE (HP*WP*Cc)     // xpad elems per batch (bf16): 1,081,600
#define PPE (HP*WP*32)     // popad/ropad elems per batch: 540,800
#define KX  576            // x-tap K (9*64)
#define KP  288            // po-tap K (9*32)
#define KT  (KX+KP)        // 864 total K, 27 MFMA steps

typedef __attribute__((ext_vector_type(8))) short short8;
typedef __attribute__((ext_vector_type(4))) float float4v;

__device__ __forceinline__ float bf2f(__hip_bfloat16 x) { return __bfloat162float(x); }
__device__ __forceinline__ __hip_bfloat16 f2bf(float x) { return __float2bfloat16(x); }
__device__ __forceinline__ float sigm(float x) { return 1.f / (1.f + expf(-x)); }

#define NW1 (64*KT)          // 55296
#define NW2 (32*KP)          // 9216
#define NW3 (Cc*Cc*Np)       // 36864  (total 101376 = 396*256)

// ---------------------------------------------------------------------------
// K1: merged prep.
// blk <4096: xpad interior | 4096..4607: popad | 4608..5003: weight packs
// ---------------------------------------------------------------------------
__global__ __launch_bounds__(256)
void k_prep(const float* __restrict__ x, const float* __restrict__ po,
            const float* __restrict__ upd_w, const float* __restrict__ rst_w,
            const float* __restrict__ out_w, const float* __restrict__ wg_w,
            const float* __restrict__ wcw,
            __hip_bfloat16* __restrict__ xp, __hip_bfloat16* __restrict__ pp,
            __hip_bfloat16* __restrict__ wall, __hip_bfloat16* __restrict__ w2,
            __hip_bfloat16* __restrict__ wt) {
  __shared__ float tile[16][65];
  int blk = blockIdx.x;
  int t = threadIdx.x;
  if (blk < 4096) {
    int wtile = blk & 7;
    int h = (blk >> 3) & 127;
    int b = blk >> 10;
    int w0 = wtile * 16;
    int wa = t & 15, cq = t >> 4;
    #pragma unroll
    for (int j = 0; j < 4; ++j) {
      int c = cq * 4 + j;
      tile[wa][c] = x[(b*Cc + c)*HW + h*Wd + w0 + wa];
    }
    __syncthreads();
    int cb = t & 63, wq = t >> 6;
    #pragma unroll
    for (int j = 0; j < 4; ++j) {
      int w = wq * 4 + j;
      xp[b*XPE + ((h+1)*WP + (w0 + w + 1))*Cc + cb] = f2bf(tile[w][cb]);
    }
  } else if (blk < 4608) {
    int pb = blk - 4096;            // b*128 + h
    int h = pb & 127;
    int b = pb >> 7;
    int w = t & 127;
    int half = t >> 7;
    for (int j = 0; j < 9; ++j) {
      int ch = half * 9 + j;
      float v = po[(b*MHc + ch)*HW + h*Wd + w];
      pp[b*PPE + ((h+1)*WP + (w+1))*32 + ch] = f2bf(v);
    }
  } else {
    int idx = (blk - 4608) * 256 + t;
    if (idx < NW1) {
      int k  = idx % KT;
      int gr = idx / KT;
      float v = 0.f;
      if (k < KX) {
        int n = k >> 6, ci = k & 63;
        if      (gr < 18) v = upd_w[(gr*(Cc+MHc) + ci)*9 + n];
        else if (gr < 36) v = rst_w[((gr-18)*(Cc+MHc) + ci)*9 + n];
        else if (gr < 54) v = out_w[((gr-36)*(Cc+MHc) + ci)*9 + n];
        else if (gr < 63) v = wg_w[((gr-54)*Cc + ci)*9 + n];
      } else {
        int kk = k - KX;
        int n = kk >> 5, jc = kk & 31;
        if (jc < 18) {
          if      (gr < 18) v = upd_w[(gr*(Cc+MHc) + Cc + jc)*9 + n];
          else if (gr < 36) v = rst_w[((gr-18)*(Cc+MHc) + Cc + jc)*9 + n];
        }
      }
      wall[idx] = f2bf(v);
    } else if (idx < NW1 + NW2) {
      int i2 = idx - NW1;
      int k  = i2 % KP;
      int oc = i2 / KP;
      int n = k >> 5, jc = k & 31;
      float v = (oc < 18 && jc < 18) ? out_w[(oc*(Cc+MHc) + Cc + jc)*9 + n] : 0.f;
      w2[i2] = f2bf(v);
    } else if (idx < NW1 + NW2 + NW3) {
      int i3 = idx - NW1 - NW2;
      int k  = i3 % 576;
      int co = i3 / 576;
      wt[i3] = f2bf(wcw[(co*Cc + (k & 63))*9 + (k >> 6)]);
    }
  }
}

// ---------------------------------------------------------------------------
// K2: all-gates MFMA GEMM (M=64 x K=864 x 16px/block).
// Epilogue: u -> u_out (= out_mn region), cx -> cx_out (= out_off region),
// ro -> LDS bounce -> coalesced ropad row, m -> pixel-major m_t.
// ---------------------------------------------------------------------------
__global__ __launch_bounds__(256)
void k_gates(const __hip_bfloat16* __restrict__ xpad,
             const __hip_bfloat16* __restrict__ popad,
             const __hip_bfloat16* __restrict__ wall,
             const float* __restrict__ po,
             const float* __restrict__ upd_b,
             const float* __restrict__ rst_b,
             const float* __restrict__ out_b,
             const float* __restrict__ wg_b,
             float* __restrict__ u_out,      // aliases out_mn
             float* __restrict__ cx_out,     // aliases out_off
             __hip_bfloat16* __restrict__ ropad,
             __hip_bfloat16* __restrict__ m_t) {
  __shared__ __align__(16) __hip_bfloat16 sh[16][KT + 8];
  __shared__ __align__(16) __hip_bfloat16 roL[16][32];
  int blk = blockIdx.x;
  int wtile = blk & 7;
  int h = (blk >> 3) & 127;
  int b = blk >> 10;
  int w0 = wtile * 16;
  int lane = threadIdx.x & 63;
  int wave = threadIdx.x >> 6;
  int t = threadIdx.x;

  ((unsigned int*)roL)[t] = 0u;      // zero all 512 bf16 (incl. ch 18..31)

  const __hip_bfloat16* xpb = xpad + b * XPE;
  const __hip_bfloat16* ppb = popad + b * PPE;
  int c32 = lane & 31, tsel = lane >> 5;

  for (int tt = 0; tt < 4; ++tt) {
    int pl = wave * 4 + tt;
    int wp = w0 + pl;
    #pragma unroll
    for (int n = 0; n < 9; ++n)
      sh[pl][n*64 + lane] = xpb[((h + n/3)*WP + wp + n%3)*Cc + lane];
    #pragma unroll
    for (int nb = 0; nb < 9; nb += 2) {
      int n = nb + tsel;
      if (n < 9)
        sh[pl][KX + n*32 + c32] = ppb[((h + n/3)*WP + wp + n%3)*32 + c32];
    }
  }
  __syncthreads();

  int mrow = lane & 15;
  int quad = lane >> 4;
  int cotile = wave * 16;
  float4v acc = {0.f, 0.f, 0.f, 0.f};
  for (int ks = 0; ks < KT/32; ++ks) {
    short8 a = *reinterpret_cast<const short8*>(
        wall + (cotile + mrow) * KT + ks * 32 + quad * 8);
    short8 bfr = *reinterpret_cast<const short8*>(
        &sh[mrow][ks * 32 + quad * 8]);
    acc = __builtin_amdgcn_mfma_f32_16x16x32_bf16(a, bfr, acc, 0, 0, 0);
  }

  int sp = h * Wd + w0 + mrow;
  #pragma unroll
  for (int r = 0; r < 4; ++r) {
    int gr = cotile + quad * 4 + r;
    float v = acc[r];
    if (gr < 18) {
      u_out[(b*MHc + gr)*HW + sp] = sigm(v + upd_b[gr]);
    } else if (gr < 36) {
      int oc = gr - 18;
      float rr = sigm(v + rst_b[oc]);
      roL[mrow][oc] = f2bf(rr * po[(b*MHc + oc)*HW + sp]);
    } else if (gr < 54) {
      int oc = gr - 36;
      cx_out[(b*MHc + oc)*HW + sp] = v + out_b[oc];
    } else if (gr < 63) {
      int nn = gr - 54;
      m_t[(b*HW + sp)*9 + nn] = f2bf(sigm(v + wg_b[nn]));
    }
  }
  __syncthreads();
  // coalesced ropad store: 16px x 32ch bf16 = 256 dwords, contiguous
  unsigned int* dst = (unsigned int*)(ropad + b*PPE + ((h+1)*WP + (w0+1))*32);
  dst[t] = ((unsigned int*)roL)[t];
}

// ---------------------------------------------------------------------------
// K3: fused stage-2 GEMM + offset/mean + deformable gather + warp GEMM.
// Block = 16px. Phases: stage ro -> GEMM2(waves 0-1)/m-load(waves 2-3) ->
// bilinear precompute -> gather -> 64x576 MFMA -> out_x.
// ---------------------------------------------------------------------------
__global__ __launch_bounds__(256)
void k_fuse(const __hip_bfloat16* __restrict__ xpad,
            const __hip_bfloat16* __restrict__ ropad,
            const __hip_bfloat16* __restrict__ w2,
            const __hip_bfloat16* __restrict__ wt,
            const __hip_bfloat16* __restrict__ m_t,
            const float* __restrict__ po,
            const float* __restrict__ mean,
            float* __restrict__ out_off,    // also cx_out (read then overwrite)
            float* __restrict__ out_mn,     // also u_out  (read then overwrite)
            float* __restrict__ out_x) {
  __shared__ __align__(16) char lbuf[16*584*2];   // union: shro / xw
  __shared__ float offL[16][18];
  __shared__ float mL[16][9];
  __shared__ __align__(16) float gw[144][4];
  __shared__ __align__(16) int   ga[144][4];
  auto shro = (__hip_bfloat16(*)[KP+8])lbuf;      // [16][296]
  auto xw   = (__hip_bfloat16(*)[584])lbuf;       // [16][584]

  int blk = blockIdx.x;
  int wtile = blk & 7;
  int h = (blk >> 3) & 127;
  int b = blk >> 10;
  int w0 = wtile * 16;
  int lane = threadIdx.x & 63;
  int wave = threadIdx.x >> 6;
  int t = threadIdx.x;

  // ---- phase 1: stage ro taps (K=288) for 16 px ----
  const __hip_bfloat16* rpb = ropad + b * PPE;
  int c32 = lane & 31, tsel = lane >> 5;
  for (int tt = 0; tt < 4; ++tt) {
    int pl = wave * 4 + tt;
    int wp = w0 + pl;
    #pragma unroll
    for (int nb = 0; nb < 9; nb += 2) {
      int n = nb + tsel;
      if (n < 9)
        shro[pl][n*32 + c32] = rpb[((h + n/3)*WP + wp + n%3)*32 + c32];
    }
  }
  __syncthreads();

  int mrow = lane & 15;
  int quad = lane >> 4;

  // ---- phase 2: waves 0-1 do GEMM2 + offset/mean; waves 2-3 load m ----
  if (wave < 2) {
    float4v acc = {0.f, 0.f, 0.f, 0.f};
    for (int ks = 0; ks < KP/32; ++ks) {
      short8 a = *reinterpret_cast<const short8*>(
          w2 + (wave*16 + mrow) * KP + ks * 32 + quad * 8);
      short8 bfr = *reinterpret_cast<const short8*>(
          &shro[mrow][ks * 32 + quad * 8]);
      acc = __builtin_amdgcn_mfma_f32_16x16x32_bf16(a, bfr, acc, 0, 0, 0);
    }
    int sp = h * Wd + w0 + mrow;
    #pragma unroll
    for (int r = 0; r < 4; ++r) {
      int gr = wave*16 + quad * 4 + r;
      if (gr < 18) {
        int gi = (b*MHc + gr)*HW + sp;
        float cand = tanhf(out_off[gi] + acc[r]);   // cx (aliased)
        float u = out_mn[gi];                       // u  (aliased)
        float p = po[gi];
        float mn = 0.5f * (mean[gi] + p);
        float off = p * (1.f - u) + cand * u + mn;
        out_off[gi] = off;
        out_mn[gi]  = mn;
        offL[mrow][gr] = off;
      }
    }
  } else {
    int base = (wave - 2) * 64 + lane;
    #pragma unroll
    for (int rep = 0; rep < 2; ++rep) {
      int id = base + rep * 128;
      if (id < 144) {
        int px = id / 9, n = id % 9;
        mL[px][n] = bf2f(m_t[(b*HW + h*Wd + w0 + px)*9 + n]);
      }
    }
  }
  __syncthreads();

  // ---- phase 3: bilinear weights/addresses (lane-invariant work, LDS in) ----
  if (t < 144) {
    int px = t / 9, n = t % 9;
    int wp = w0 + px;
    float ox = offL[px][n];
    float oy = offL[px][9 + n];
    float mn = mL[px][n];
    float px_ = (float)(h + 1) + (float)(n / 3 - 1) + ox;
    float py_ = (float)(wp + 1) + (float)(n % 3 - 1) + oy;
    float fx = floorf(px_), fy = floorf(py_);
    float xlt = fminf(fmaxf(fx,       0.f), 129.f);
    float ylt = fminf(fmaxf(fy,       0.f), 129.f);
    float xrb = fminf(fmaxf(fx + 1.f, 0.f), 129.f);
    float yrb = fminf(fmaxf(fy + 1.f, 0.f), 129.f);
    float pxc = fminf(fmaxf(px_, 0.f), 129.f);
    float pyc = fminf(fmaxf(py_, 0.f), 129.f);
    float glt = (1.f + xlt - pxc) * (1.f + ylt - pyc);
    float grb = (1.f - xrb + pxc) * (1.f - yrb + pyc);
    float glb = (1.f + xlt - pxc) * (1.f - yrb + pyc);
    float grt = (1.f - xrb + pxc) * (1.f + ylt - pyc);
    int ixl = (int)xlt, iyl = (int)ylt, ixr = (int)xrb, iyr = (int)yrb;
    gw[t][0] = glt * mn; gw[t][1] = grb * mn;
    gw[t][2] = glb * mn; gw[t][3] = grt * mn;
    ga[t][0] = (ixl * WP + iyl) * Cc; ga[t][1] = (ixr * WP + iyr) * Cc;
    ga[t][2] = (ixl * WP + iyr) * Cc; ga[t][3] = (ixr * WP + iyl) * Cc;
  }
  __syncthreads();

  // ---- phase 4: gather (xw overwrites shro region — consumed above) ----
  const __hip_bfloat16* xpb = xpad + b * XPE;
  for (int tt = 0; tt < 4; ++tt) {
    int pl = wave * 4 + tt;
    #pragma unroll
    for (int n = 0; n < Np; ++n) {
      int q = pl * 9 + n;
      float4v g = *reinterpret_cast<const float4v*>(gw[q]);
      int a0 = ga[q][0], a1 = ga[q][1], a2 = ga[q][2], a3 = ga[q][3];
      float v0 = bf2f(xpb[a0 + lane]);
      float v1 = bf2f(xpb[a1 + lane]);
      float v2 = bf2f(xpb[a2 + lane]);
      float v3 = bf2f(xpb[a3 + lane]);
      xw[pl][n * 64 + lane] = f2bf(g.x*v0 + g.y*v1 + g.z*v2 + g.w*v3);
    }
  }
  __syncthreads();

  // ---- phase 5: warp GEMM 64x576 ----
  int cotile = wave * 16;
  float4v acc = {0.f, 0.f, 0.f, 0.f};
  for (int ks = 0; ks < 18; ++ks) {
    short8 a = *reinterpret_cast<const short8*>(
        wt + (cotile + mrow) * 576 + ks * 32 + quad * 8);
    short8 bfr = *reinterpret_cast<const short8*>(
        &xw[mrow][ks * 32 + quad * 8]);
    acc = __builtin_amdgcn_mfma_f32_16x16x32_bf16(a, bfr, acc, 0, 0, 0);
  }
  #pragma unroll
  for (int r = 0; r < 4; ++r) {
    int co = cotile + quad * 4 + r;
    out_x[((b * Cc + co) * Hh + h) * Wd + w0 + mrow] = acc[r];
  }
}

// ---------------------------------------------------------------------------
// Fallback (R9-verified scalar pipeline; zero ws)
// ---------------------------------------------------------------------------
__global__ void f_convAB(const float* __restrict__ x, const float* __restrict__ po,
                         const float* __restrict__ wA, const float* __restrict__ bA,
                         const float* __restrict__ wB, const float* __restrict__ bB,
                         float* __restrict__ u_scr, float* __restrict__ ro_scr) {
  int idx = blockIdx.x * 256 + threadIdx.x;
  if (idx >= Bn * MHc * HW) return;
  int w = idx & 127, h = (idx >> 7) & 127, oc = (idx >> 14) % MHc, b = idx / (MHc*HW);
  float accA = bA[oc], accB = bB[oc];
  const float* xb = x + b*Cc*HW; const float* pb = po + b*MHc*HW;
  for (int ic = 0; ic < Cc + MHc; ++ic) {
    const float* src = (ic < Cc) ? (xb + ic*HW) : (pb + (ic-Cc)*HW);
    const float* wa = wA + (oc*(Cc+MHc)+ic)*9; const float* wb = wB + (oc*(Cc+MHc)+ic)*9;
    for (int kh = 0; kh < 3; ++kh) { int hh = h+kh-1; if ((unsigned)hh >= Hh) continue;
      for (int kw = 0; kw < 3; ++kw) { int ww = w+kw-1; if ((unsigned)ww >= Wd) continue;
        float v = src[hh*Wd+ww]; accA += v*wa[kh*3+kw]; accB += v*wb[kh*3+kw]; } }
  }
  u_scr[idx] = sigm(accA); ro_scr[idx] = sigm(accB) * pb[oc*HW + h*Wd + w];
}
__global__ void f_convC(const float* __restrict__ x, const float* __restrict__ po,
                        const float* __restrict__ mean, const float* __restrict__ wC,
                        const float* __restrict__ bC, const float* __restrict__ u_scr,
                        const float* __restrict__ ro_scr, float* __restrict__ out_off,
                        float* __restrict__ out_mean) {
  int idx = blockIdx.x * 256 + threadIdx.x;
  if (idx >= Bn * MHc * HW) return;
  int w = idx & 127, h = (idx >> 7) & 127, oc = (idx >> 14) % MHc, b = idx / (MHc*HW);
  float acc = bC[oc];
  const float* xb = x + b*Cc*HW; const float* rb = ro_scr + b*MHc*HW;
  for (int ic = 0; ic < Cc + MHc; ++ic) {
    const float* src = (ic < Cc) ? (xb + ic*HW) : (rb + (ic-Cc)*HW);
    const float* wv = wC + (oc*(Cc+MHc)+ic)*9;
    for (int kh = 0; kh < 3; ++kh) { int hh = h+kh-1; if ((unsigned)hh >= Hh) continue;
      for (int kw = 0; kw < 3; ++kw) { int ww = w+kw-1; if ((unsigned)ww >= Wd) continue;
        acc += src[hh*Wd+ww]*wv[kh*3+kw]; } }
  }
  float cand = tanhf(acc); float u = u_scr[idx]; float p = po[idx];
  float mn = 0.5f*(mean[idx]+p);
  out_off[idx] = p*(1.f-u)+cand*u+mn; out_mean[idx] = mn;
}
__global__ __launch_bounds__(256)
void f_warp(const float* __restrict__ x, const float* __restrict__ off_f,
            const float* __restrict__ wg, const float* __restrict__ bg,
            const float* __restrict__ wc, float* __restrict__ out) {
  __shared__ float mred[4][Np][64]; __shared__ float mval[4][Np];
  __shared__ float xwv[4][Np][64];
  int lane = threadIdx.x & 63, wave = threadIdx.x >> 6;
  int p = blockIdx.x * 4 + wave;
  int b = p >> 14, rem = p & 16383, h = rem >> 7, w = rem & 127;
  const float* xc = x + (b*Cc + lane)*HW;
  float part[Np];
  for (int n = 0; n < Np; ++n) part[n] = 0.f;
  for (int kh = 0; kh < 3; ++kh) { int hh = h+kh-1; if ((unsigned)hh >= Hh) continue;
    for (int kw = 0; kw < 3; ++kw) { int ww = w+kw-1; if ((unsigned)ww >= Wd) continue;
      float v = xc[hh*Wd+ww];
      for (int n = 0; n < Np; ++n) part[n] += v*wg[(n*Cc+lane)*9+kh*3+kw]; } }
  for (int n = 0; n < Np; ++n) mred[wave][n][lane] = part[n];
  __syncthreads();
  if (lane < Np) { float s = bg[lane];
    for (int c = 0; c < Cc; ++c) s += mred[wave][lane][c];
    mval[wave][lane] = sigm(s); }
  __syncthreads();
  const float* offb = off_f + b*MHc*HW; int sp = h*Wd + w;
  for (int n = 0; n < Np; ++n) {
    float px = (float)(h+1) + (float)(n/3-1) + offb[n*HW+sp];
    float py = (float)(w+1) + (float)(n%3-1) + offb[(9+n)*HW+sp];
    float fxq = floorf(px), fyq = floorf(py);
    float xlt = fminf(fmaxf(fxq,0.f),129.f), ylt = fminf(fmaxf(fyq,0.f),129.f);
    float xrb = fminf(fmaxf(fxq+1.f,0.f),129.f), yrb = fminf(fmaxf(fyq+1.f,0.f),129.f);
    float pxc = fminf(fmaxf(px,0.f),129.f), pyc = fminf(fmaxf(py,0.f),129.f);
    float glt = (1.f+xlt-pxc)*(1.f+ylt-pyc), grb = (1.f-xrb+pxc)*(1.f-yrb+pyc);
    float glb = (1.f+xlt-pxc)*(1.f-yrb+pyc), grt = (1.f-xrb+pxc)*(1.f+ylt-pyc);
    int ixl=(int)xlt, iyl=(int)ylt, ixr=(int)xrb, iyr=(int)yrb;
    float vlt=0.f,vrb=0.f,vlb=0.f,vrt=0.f;
    if (ixl>=1&&ixl<=Hh&&iyl>=1&&iyl<=Wd) vlt = xc[(ixl-1)*Wd+(iyl-1)];
    if (ixr>=1&&ixr<=Hh&&iyr>=1&&iyr<=Wd) vrb = xc[(ixr-1)*Wd+(iyr-1)];
    if (ixl>=1&&ixl<=Hh&&iyr>=1&&iyr<=Wd) vlb = xc[(ixl-1)*Wd+(iyr-1)];
    if (ixr>=1&&ixr<=Hh&&iyl>=1&&iyl<=Wd) vrt = xc[(ixr-1)*Wd+(iyl-1)];
    xwv[wave][n][lane] = (glt*vlt+grb*vrb+glb*vlb+grt*vrt)*mval[wave][n];
  }
  __syncthreads();
  float acc = 0.f;
  for (int c = 0; c < Cc; ++c)
    for (int n = 0; n < Np; ++n)
      acc += xwv[wave][n][c]*wc[(lane*Cc+c)*9+n];
  out[(b*Cc+lane)*HW + h*Wd + w] = acc;
}

// ---------------------------------------------------------------------------
extern "C" void kernel_launch(void* const* d_in, const int* in_sizes, int n_in,
                              void* d_out, int out_size, void* d_ws, size_t ws_size,
                              hipStream_t stream) {
  (void)in_sizes; (void)n_in; (void)out_size;
  const float* x_t   = (const float*)d_in[0];
  const float* po    = (const float*)d_in[1];
  const float* mean  = (const float*)d_in[2];
  const float* upd_w = (const float*)d_in[3];
  const float* upd_b = (const float*)d_in[4];
  const float* rst_w = (const float*)d_in[5];
  const float* rst_b = (const float*)d_in[6];
  const float* out_w = (const float*)d_in[7];
  const float* out_b = (const float*)d_in[8];
  const float* wg_w  = (const float*)d_in[9];
  const float* wg_b  = (const float*)d_in[10];
  const float* wcw   = (const float*)d_in[11];

  float* out_x   = (float*)d_out;            // [4,64,128,128]
  float* out_off = out_x + 4194304;          // [4,18,128,128]
  float* out_mn  = out_off + 1179648;        // [4,18,128,128]

  char* ws = (char*)d_ws;
  __hip_bfloat16* xpad  = (__hip_bfloat16*)(ws + 0);          //  8,652,800
  __hip_bfloat16* popad = (__hip_bfloat16*)(ws + 8652800);    //  4,326,400
  __hip_bfloat16* ropad = (__hip_bfloat16*)(ws + 12979200);   //  4,326,400
  __hip_bfloat16* wall  = (__hip_bfloat16*)(ws + 17305600);   //    110,592
  __hip_bfloat16* w2    = (__hip_bfloat16*)(ws + 17416192);   //     18,432
  __hip_bfloat16* wt_bf = (__hip_bfloat16*)(ws + 17434624);   //     73,728
  __hip_bfloat16* m_t   = (__hip_bfloat16*)(ws + 17508352);   //  1,179,648
  const size_t WS_NEED = 18688000;

  if (ws_size >= WS_NEED) {
    hipMemsetAsync(d_ws, 0, 17305600, stream);   // xpad+popad+ropad borders
    hipLaunchKernelGGL(k_prep,  dim3(5004), dim3(256), 0, stream,
                       x_t, po, upd_w, rst_w, out_w, wg_w, wcw,
                       xpad, popad, wall, w2, wt_bf);
    // u -> out_mn region, cx -> out_off region (exact [B,18,HW] aliases;
    // k_fuse reads each address before overwriting it)
    hipLaunchKernelGGL(k_gates, dim3(4096), dim3(256), 0, stream,
                       xpad, popad, wall, po, upd_b, rst_b, out_b, wg_b,
                       out_mn, out_off, ropad, m_t);
    hipLaunchKernelGGL(k_fuse,  dim3(4096), dim3(256), 0, stream,
                       xpad, ropad, w2, wt_bf, m_t, po, mean,
                       out_off, out_mn, out_x);
  } else {
    float* u_scr  = out_x;
    float* cx_scr = out_x + 1179648;
    hipLaunchKernelGGL(f_convAB, dim3(4608), dim3(256), 0, stream,
                       x_t, po, upd_w, upd_b, rst_w, rst_b, u_scr, cx_scr);
    hipLaunchKernelGGL(f_convC,  dim3(4608), dim3(256), 0, stream,
                       x_t, po, mean, out_w, out_b, u_scr, cx_scr,
                       out_off, out_mn);
    hipLaunchKernelGGL(f_warp,   dim3(16384), dim3(256), 0, stream,
                       x_t, out_off, wg_w, wg_b, wcw, out_x);
  }
}